// Round 12
// baseline (4652.875 us; speedup 1.0000x reference)
//
#include <hip/hip_runtime.h>
#include <stdint.h>

typedef unsigned short u16;
typedef __attribute__((ext_vector_type(8))) short short8;
typedef __attribute__((ext_vector_type(4))) float f32x4;

#define DEVI __device__ __forceinline__

static constexpr int TT = 768;
static constexpr int CC = 2048;
static constexpr int MM = 3072;
static constexpr int HH = 32;

DEVI float b2f(u16 u){ union{float f; unsigned int i;} x; x.i = ((unsigned int)u)<<16; return x.f; }
DEVI float b2fs(short s){ return b2f((u16)s); }
DEVI u16 f2b(float f){
  unsigned int u = __builtin_bit_cast(unsigned int, f);
  unsigned int r = (u + 0x7fffu + ((u>>16)&1u)) >> 16;
  return (u16)r;
}

DEVI void gload16(const void* g, void* s){
  __builtin_amdgcn_global_load_lds((const __attribute__((address_space(1))) void*)g,
                                   (__attribute__((address_space(3))) void*)s, 16, 0, 0);
}

// ---------------- fill first n floats of out with constant (probe marker)
__global__ __launch_bounds__(256) void k_fillf(float* __restrict__ out, float v, int n){
  for (int i = blockIdx.x*256 + threadIdx.x; i < n; i += gridDim.x*256) out[i] = v;
}

// ---------------- transpose + f32->bf16 convert: dst[c*ldd + r] = src[r*Cn + c]
__global__ void k_tpose(const float* __restrict__ src, int R, int Cn, u16* __restrict__ dst, int ldd){
  __shared__ float tile[32][33];
  int c0 = blockIdx.x*32, r0 = blockIdx.y*32;
  #pragma unroll
  for (int i=0;i<4;++i){
    int r = r0 + threadIdx.y + i*8, c = c0 + threadIdx.x;
    tile[threadIdx.y + i*8][threadIdx.x] = (r<R && c<Cn) ? src[(size_t)r*Cn + c] : 0.f;
  }
  __syncthreads();
  #pragma unroll
  for (int i=0;i<4;++i){
    int c = c0 + threadIdx.y + i*8, r = r0 + threadIdx.x;
    if (c<Cn && r<R) dst[(size_t)c*ldd + r] = f2b(tile[threadIdx.x][threadIdx.y + i*8]);
  }
}

// ---------------- layernorm f32 -> bf16
__global__ __launch_bounds__(256) void k_lnb(const float* __restrict__ in, const float* __restrict__ w,
                                             const float* __restrict__ bias, u16* __restrict__ out){
  __shared__ float red[8];
  int m = blockIdx.x;
  const float* x = in + (size_t)m*CC;
  float v[8]; float s=0.f, ss=0.f;
  #pragma unroll
  for (int i=0;i<8;++i){ v[i] = x[threadIdx.x + i*256]; s += v[i]; ss += v[i]*v[i]; }
  #pragma unroll
  for (int o=32;o;o>>=1){ s += __shfl_xor(s,o); ss += __shfl_xor(ss,o); }
  int wid = threadIdx.x>>6;
  if ((threadIdx.x&63)==0){ red[wid]=s; red[4+wid]=ss; }
  __syncthreads();
  s  = red[0]+red[1]+red[2]+red[3];
  ss = red[4]+red[5]+red[6]+red[7];
  float mean = s*(1.f/2048.f);
  float var  = ss*(1.f/2048.f) - mean*mean;
  float rstd = rsqrtf(fmaxf(var,0.f) + 1e-5f);
  #pragma unroll
  for (int i=0;i<8;++i){
    int c = threadIdx.x + i*256;
    out[(size_t)m*CC + c] = f2b((v[i]-mean)*rstd*w[c] + bias[c]);
  }
}

// ---------------- token-shift mixes
__global__ __launch_bounds__(256) void k_mixA(const u16* __restrict__ xn,
  const float* __restrict__ cw, const float* __restrict__ ca, const float* __restrict__ cv,
  const float* __restrict__ cg,
  u16* __restrict__ ow, u16* __restrict__ oa, u16* __restrict__ ov, u16* __restrict__ og)
{
  int m = blockIdx.x; int t = m % TT;
  const u16* cur = xn + (size_t)m*CC;
  const u16* prv = cur - CC;
  bool has = (t>0);
  #pragma unroll
  for (int i=0;i<8;++i){
    int c = threadIdx.x + i*256;
    float xc = b2f(cur[c]);
    float xx = (has ? b2f(prv[c]) : 0.f) - xc;
    size_t o = (size_t)m*CC + c;
    ow[o]=f2b(xc + xx*cw[c]); oa[o]=f2b(xc + xx*ca[c]);
    ov[o]=f2b(xc + xx*cv[c]); og[o]=f2b(xc + xx*cg[c]);
  }
}

__global__ __launch_bounds__(256) void k_mixB(const u16* __restrict__ xn,
  const float* __restrict__ cr, const float* __restrict__ ck,
  u16* __restrict__ orr, u16* __restrict__ ok)
{
  int m = blockIdx.x; int t = m % TT;
  const u16* cur = xn + (size_t)m*CC;
  const u16* prv = cur - CC;
  bool has = (t>0);
  #pragma unroll
  for (int i=0;i<8;++i){
    int c = threadIdx.x + i*256;
    float xc = b2f(cur[c]);
    float xx = (has ? b2f(prv[c]) : 0.f) - xc;
    size_t o = (size_t)m*CC + c;
    orr[o]=f2b(xc + xx*cr[c]); ok[o]=f2b(xc + xx*ck[c]);
  }
}

__global__ __launch_bounds__(256) void k_mix1(const u16* __restrict__ xn, const float* __restrict__ cf,
                                              u16* __restrict__ out){
  int m = blockIdx.x; int t = m % TT;
  const u16* cur = xn + (size_t)m*CC;
  const u16* prv = cur - CC;
  bool has = (t>0);
  #pragma unroll
  for (int i=0;i<8;++i){
    int c = threadIdx.x + i*256;
    float xc = b2f(cur[c]);
    float xx = (has ? b2f(prv[c]) : 0.f) - xc;
    out[(size_t)m*CC + c] = f2b(xc + xx*cf[c]);
  }
}

// ---------------- bf16 MFMA GEMM, 128x128 tile, BK=32, 2-phase dbuf pipeline, XCD swizzle
// amode: 0 A=A0 | 1 A by ntile (0:A0 1:A1 else:A2) | 2 A by ntile>>4 (0:A0 1:A1 else:A2)
// emode: 0 f32 | 1 decay-scatter f32 | 2 sigmoid bf16 | 3 aux+v f32 | 4 relu^2 bf16
//        5 aux+v bf16 | 6 v bf16 | 7 h1act bf16 | 8 scatter bf16 | 9 sigmoid scatter
//        10 rkv scatter (col>>11 -> C0/C1/C2) | 11 sigmoid bf16 at col+384
__global__ __launch_bounds__(256,2) void k_gemm(
    const u16* A0, const u16* A1, const u16* A2,
    int amode, int lda,
    const u16* __restrict__ BT, int ldb,
    void* C0, void* C1, void* C2, int ldc, int K,
    int emode, const float* __restrict__ aux)
{
  const int tid = threadIdx.x;
  const int w = tid>>6, l = tid&63;

  // bijective XCD chunk swizzle (m204)
  const int NT = gridDim.x;
  const int nwg = NT * gridDim.y;
  int bid = blockIdx.y * NT + blockIdx.x;
  int q = nwg >> 3, r = nwg & 7;
  int xcd = bid & 7, pos = bid >> 3;
  int nid = (xcd < r ? xcd*(q+1) : r*(q+1) + (xcd-r)*q) + pos;
  const int ntile = nid % NT;
  const int mtile = nid / NT;

  const u16* A = A0;
  if (amode==1){ A = (ntile==0)?A0:(ntile==1)?A1:A2; }
  else if (amode==2){ int g = ntile>>4; A = (g==0)?A0:(g==1)?A1:A2; }

  __shared__ __align__(16) u16 As[2][4096];
  __shared__ __align__(16) u16 Bs[2][4096];

  const int sr = w*16 + (l>>2);
  const int sk = (l&3)*8;
  const u16* Ag = A  + (size_t)(mtile*128 + sr)*lda + sk;
  const u16* Bg = BT + (size_t)(ntile*128 + sr)*ldb + sk;
  const size_t a64 = (size_t)64*lda, b64 = (size_t)64*ldb;
  const int wo = w*512;

  const int wm = w>>1, wn = w&1;
  const int fr = l&15, fk = (l>>4)*8;
  const int aoff = (wm*64 + fr)*32 + fk;
  const int boff = (wn*64 + fr)*32 + fk;

  f32x4 acc[4][4];
  const f32x4 zz = {0.f,0.f,0.f,0.f};
  #pragma unroll
  for (int mi=0;mi<4;++mi)
    #pragma unroll
    for (int ni=0;ni<4;++ni) acc[mi][ni] = zz;

  const int nt = K >> 5;
  gload16(Ag,        As[0] + wo);
  gload16(Ag + a64,  As[0] + wo + 2048);
  gload16(Bg,        Bs[0] + wo);
  gload16(Bg + b64,  Bs[0] + wo + 2048);
  __syncthreads();
  int cur = 0;
  for (int t=0; t<nt; ++t){
    if (t+1 < nt){
      int k0 = (t+1) << 5;
      gload16(Ag + k0,        As[cur^1] + wo);
      gload16(Ag + a64 + k0,  As[cur^1] + wo + 2048);
      gload16(Bg + k0,        Bs[cur^1] + wo);
      gload16(Bg + b64 + k0,  Bs[cur^1] + wo + 2048);
    }
    short8 af[4], bfr[4];
    #pragma unroll
    for (int mi=0;mi<4;++mi) af[mi]  = *(const short8*)(As[cur] + aoff + mi*512);
    #pragma unroll
    for (int ni=0;ni<4;++ni) bfr[ni] = *(const short8*)(Bs[cur] + boff + ni*512);
    #pragma unroll
    for (int mi=0;mi<4;++mi)
      #pragma unroll
      for (int ni=0;ni<4;++ni)
        acc[mi][ni] = __builtin_amdgcn_mfma_f32_16x16x32_bf16(af[mi], bfr[ni], acc[mi][ni], 0,0,0);
    __syncthreads();
    cur ^= 1;
  }

  const int rb0 = mtile*128 + wm*64 + (l>>4)*4;
  const int cb0 = ntile*128 + wn*64 + fr;
  #pragma unroll
  for (int mi=0;mi<4;++mi){
    #pragma unroll
    for (int ni=0;ni<4;++ni){
      #pragma unroll
      for (int q2=0;q2<4;++q2){
        int row = rb0 + mi*16 + q2;
        int col = cb0 + ni*16;
        float v = acc[mi][ni][q2];
        if (emode==0){
          ((float*)C0)[(size_t)row*ldc + col] = v;
        } else if (emode==1){
          float valw = aux[col] + v;
          float zneg = -valw;
          float sp = (zneg > 20.f) ? zneg : log1pf(expf(zneg));
          float wlog = -sp - 0.5f;
          float dec = expf(-expf(wlog));
          int b_ = row/TT, t_ = row - b_*TT;
          int h_ = col>>6, n_ = col&63;
          ((float*)C0)[((size_t)(b_*HH + h_)*TT + t_)*64 + n_] = dec;
        } else if (emode==2){
          float s = 1.f/(1.f+expf(-(aux[col]+v)));
          ((u16*)C0)[(size_t)row*ldc + col] = f2b(s);
        } else if (emode==3){
          ((float*)C0)[(size_t)row*ldc + col] = aux[(size_t)row*ldc + col] + v;
        } else if (emode==4){
          float r_ = fmaxf(v, 0.f);
          ((u16*)C0)[(size_t)row*ldc + col] = f2b(r_*r_);
        } else if (emode==5){
          ((u16*)C0)[(size_t)row*ldc + col] = f2b(aux[(size_t)row*ldc + col] + v);
        } else if (emode==6){
          ((u16*)C0)[(size_t)row*ldc + col] = f2b(v);
        } else if (emode==7){
          float r_ = v;
          if (col < 128) r_ = tanhf(v);
          else if (col >= 384) r_ = 1.f/(1.f+expf(-v));
          ((u16*)C0)[(size_t)row*ldc + col] = f2b(r_);
        } else if (emode==8){
          int b_ = row/TT, t_ = row - b_*TT;
          int h_ = col>>6, n_ = col&63;
          ((u16*)C0)[((size_t)(b_*HH + h_)*TT + t_)*64 + n_] = f2b(v);
        } else if (emode==9){
          float s = 1.f/(1.f+expf(-(aux[col]+v)));
          int b_ = row/TT, t_ = row - b_*TT;
          int h_ = col>>6, n_ = col&63;
          ((u16*)C0)[((size_t)(b_*HH + h_)*TT + t_)*64 + n_] = f2b(s);
        } else if (emode==10){
          int g = col>>11, c2 = col&2047;
          int b_ = row/TT, t_ = row - b_*TT;
          int h_ = c2>>6, n_ = c2&63;
          u16* dst = (g==0)?(u16*)C0:(g==1)?(u16*)C1:(u16*)C2;
          dst[((size_t)(b_*HH + h_)*TT + t_)*64 + n_] = f2b(v);
        } else { // 11: sigmoid -> bf16 at col+384 (g-part of H1b, ldc=640)
          float s = 1.f/(1.f+expf(-v));
          ((u16*)C0)[(size_t)row*ldc + (col+384)] = f2b(s);
        }
      }
    }
  }
}

// ---------------- rec prep: k,v in place; a,b to f32
__global__ __launch_bounds__(256) void k_make_rec3(
  u16* __restrict__ ksc, u16* __restrict__ vsc,
  const u16* __restrict__ asc, const u16* __restrict__ gsc,
  float* __restrict__ af, float* __restrict__ bf,
  const float* __restrict__ v_first, const float* __restrict__ k_k, const float* __restrict__ k_a)
{
  int idx = blockIdx.x*4 + (threadIdx.x>>6);
  int l = threadIdx.x & 63;
  int bh = idx / TT, t = idx - bh*TT;
  int b = bh >> 5, h = bh & 31;
  int c = h*64 + l;
  size_t off = (size_t)idx*64 + l;
  size_t mo = ((size_t)b*TT + t)*CC + c;
  float kq = b2f(ksc[off]);
  float vv = b2f(vsc[off]);
  float aa = b2f(asc[off]);
  float sg = b2f(gsc[off]);
  float vf = v_first[mo];
  float kkr = kq * k_k[c];
  float s2 = kkr*kkr;
  #pragma unroll
  for (int o=32;o;o>>=1) s2 += __shfl_xor(s2,o);
  float kk = kkr / fmaxf(sqrtf(s2), 1e-12f);
  ksc[off] = f2b(kq*(1.f + (aa-1.f)*k_a[c]));
  vsc[off] = f2b(vv + (vf-vv)*sg);
  af[off] = -kk;
  bf[off] = kk*aa;
}

// ---------------- RWKV7 recurrence
struct StepB { f32x4 d[4]; f32x4 a[4]; f32x4 b[4]; short8 r[2], k[2]; float vi; };

DEVI void loadStep(StepB& sb, const float* __restrict__ dP, const float* __restrict__ aP,
                   const float* __restrict__ bP, const u16* __restrict__ rP,
                   const u16* __restrict__ kP, const u16* __restrict__ vP,
                   size_t off, size_t voff){
  const float* dp = dP + off;
  const float* ap = aP + off;
  const float* bp = bP + off;
  #pragma unroll
  for (int q=0;q<4;++q){
    sb.d[q] = *(const f32x4*)(dp+4*q);
    sb.a[q] = *(const f32x4*)(ap+4*q);
    sb.b[q] = *(const f32x4*)(bp+4*q);
  }
  const short8* rp = (const short8*)(rP + off);
  const short8* kp = (const short8*)(kP + off);
  sb.r[0]=rp[0]; sb.r[1]=rp[1];
  sb.k[0]=kp[0]; sb.k[1]=kp[1];
  sb.vi = b2f(vP[voff]);
}

DEVI float stepCompute(const StepB& sb, float S[16]){
  float sa = 0.f;
  #pragma unroll
  for (int q=0;q<16;++q) sa += S[q]*sb.a[q>>2][q&3];
  sa += __shfl_xor(sa,16); sa += __shfl_xor(sa,32);
  float yv = 0.f;
  #pragma unroll
  for (int q=0;q<16;++q){
    float Sq = S[q]*sb.d[q>>2][q&3] + sa*sb.b[q>>2][q&3] + sb.vi*b2fs(sb.k[q>>3][q&7]);
    S[q] = Sq;
    yv += Sq*b2fs(sb.r[q>>3][q&7]);
  }
  yv += __shfl_xor(yv,16); yv += __shfl_xor(yv,32);
  return yv;
}

__global__ __launch_bounds__(256,1) void k_rwkv(
    const float* __restrict__ decay, const float* __restrict__ af, const float* __restrict__ bf,
    const u16* __restrict__ rb, const u16* __restrict__ kb, const u16* __restrict__ vb,
    u16* __restrict__ y)
{
  int bh = blockIdx.x;
  int b = bh>>5, h = bh&31;
  int tid = threadIdx.x, w = tid>>6, l = tid&63;
  int i = w*16 + (l&15);
  int cch = l>>4;
  int j0 = cch*16;
  const size_t base = (size_t)bh * (TT*64);
  float S[16];
  #pragma unroll
  for (int q=0;q<16;++q) S[q]=0.f;

  size_t yb = (size_t)b*TT*CC + h*64 + i;
  StepB sA, sB;
  loadStep(sA, decay, af, bf, rb, kb, vb, base + j0, base + i);
  for (int t=0;t<TT;t+=2){
    loadStep(sB, decay, af, bf, rb, kb, vb, base + (size_t)(t+1)*64 + j0, base + (size_t)(t+1)*64 + i);
    float y0 = stepCompute(sA, S);
    if (cch==0) y[yb + (size_t)t*CC] = f2b(y0);
    if (t+2 < TT)
      loadStep(sA, decay, af, bf, rb, kb, vb, base + (size_t)(t+2)*64 + j0, base + (size_t)(t+2)*64 + i);
    float y1 = stepCompute(sB, S);
    if (cch==0) y[yb + (size_t)(t+1)*CC] = f2b(y1);
  }
}

// ---------------- groupnorm + rk*v + gate -> z bf16
__global__ __launch_bounds__(256) void k_gn(
  const u16* __restrict__ y, const u16* __restrict__ rb, const u16* __restrict__ kb,
  const u16* __restrict__ vb, const float* __restrict__ r_k,
  const float* __restrict__ gnw, const float* __restrict__ gnb,
  const u16* __restrict__ gg, u16* __restrict__ z)
{
  int idx = blockIdx.x*4 + (threadIdx.x>>6);
  int l = threadIdx.x&63;
  int m = idx>>5, h = idx&31;
  int c = h*64 + l;
  size_t mo = (size_t)m*CC + c;
  float yv = b2f(y[mo]);
  float s = yv;
  #pragma unroll
  for (int o=32;o;o>>=1) s += __shfl_xor(s,o);
  float mean = s*(1.f/64.f);
  float dv = yv - mean;
  float vs = dv*dv;
  #pragma unroll
  for (int o=32;o;o>>=1) vs += __shfl_xor(vs,o);
  float gn = dv*rsqrtf(vs*(1.f/64.f) + 6.4e-4f)*gnw[c] + gnb[c];
  size_t ro = ((size_t)((m/TT)*HH + h)*TT + (m%TT))*64 + l;
  float rv=b2f(rb[ro]), kv=b2f(kb[ro]), vv=b2f(vb[ro]);
  float p = rv*kv*r_k[c];
  #pragma unroll
  for (int o=32;o;o>>=1) p += __shfl_xor(p,o);
  z[mo] = f2b((gn + p*vv)*b2f(gg[mo]));
}

extern "C" void kernel_launch(void* const* d_in, const int* in_sizes, int n_in,
                              void* d_out, int out_size, void* d_ws, size_t ws_size,
                              hipStream_t stream)
{
  (void)out_size;
  const float* x      = (const float*)d_in[0];
  const float* v_first= (const float*)d_in[1];
  const float* ln1_w  = (const float*)d_in[2];
  const float* ln1_b  = (const float*)d_in[3];
  const float* ln2_w  = (const float*)d_in[4];
  const float* ln2_b  = (const float*)d_in[5];
  const float* x_r    = (const float*)d_in[6];
  const float* x_w    = (const float*)d_in[7];
  const float* x_k    = (const float*)d_in[8];
  const float* x_v    = (const float*)d_in[9];
  const float* x_a    = (const float*)d_in[10];
  const float* x_g    = (const float*)d_in[11];
  const float* w0     = (const float*)d_in[12];
  const float* w1     = (const float*)d_in[13];
  const float* w2     = (const float*)d_in[14];
  const float* a0     = (const float*)d_in[15];
  const float* a1     = (const float*)d_in[16];
  const float* a2     = (const float*)d_in[17];
  const float* v0     = (const float*)d_in[18];
  const float* v1     = (const float*)d_in[19];
  const float* v2     = (const float*)d_in[20];
  const float* g1     = (const float*)d_in[21];
  const float* g2     = (const float*)d_in[22];
  const float* k_k    = (const float*)d_in[23];
  const float* k_a    = (const float*)d_in[24];
  const float* r_k    = (const float*)d_in[25];
  const float* W_r    = (const float*)d_in[26];
  const float* W_k    = (const float*)d_in[27];
  const float* W_v    = (const float*)d_in[28];
  const float* W_o    = (const float*)d_in[29];
  const float* gn_w   = (const float*)d_in[30];
  const float* gn_b   = (const float*)d_in[31];
  const float* ffn_x_k= (const float*)d_in[32];
  const float* W_key  = (const float*)d_in[33];
  const float* W_val  = (const float*)d_in[34];

  const size_t ME = (size_t)MM*CC;   // 6291456
  float* outF = (float*)d_out;       // OUTPUT IS FLOAT32 (confirmed r10)

  bool ok = (n_in==35)
    && in_sizes[0]==6291456 && in_sizes[1]==6291456 && in_sizes[2]==2048
    && in_sizes[12]==2048 && in_sizes[13]==196608 && in_sizes[14]==196608
    && in_sizes[16]==196608 && in_sizes[19]==131072 && in_sizes[21]==524288
    && in_sizes[25]==2048 && in_sizes[26]==4194304 && in_sizes[33]==16777216
    && in_sizes[34]==16777216;
  if (!ok){
    k_fillf<<<2048, 256, 0, stream>>>(outF, 1099511627776.f /*2^40*/, (int)ME);
    return;
  }

  constexpr size_t WS_NEED = 125829120 + 12582912;
  if (ws_size < WS_NEED){
    k_fillf<<<2048, 256, 0, stream>>>(outF, (float)(1u<<21) * (float)(ws_size>>20), (int)ME);
    return;
  }
  char* ws = (char*)d_ws;
  float* decay = (float*)(ws + 0);            // G: decay -> x1
  float* x1    = (float*)(ws + 0);
  u16* xn   = (u16*)(ws + 25165824);          // A: xn -> WT(Wo) -> WbigT head
  u16* WT   = (u16*)(ws + 25165824);
  float* bf32 = (float*)(ws + 25165824);      // [24,48M)
  u16* xw  = (u16*)(ws + 37748736);           // B: xw -> xr -> bf32 tail -> xn2
  u16* xr  = (u16*)(ws + 37748736);
  u16* xn2 = (u16*)(ws + 37748736);
  float* af32 = (float*)(ws + 50331648);      // [48,72M)
  u16* xa  = (u16*)(ws + 50331648);           // C: xa -> xk -> af32 head
  u16* xk  = (u16*)(ws + 50331648);
  u16* xv  = (u16*)(ws + 62914560);           // D: xv -> af32 tail -> kf head
  u16* kf  = (u16*)(ws + 62914560);           // [60,108M)
  u16* xg  = (u16*)(ws + 75497472);           // E: xg -> rsc
  u16* rsc = (u16*)(ws + 75497472);
  char* Fs = ws + 88080384;                   // F: small weights + H1b -> ksc
  u16* B1T = (u16*)(Fs);
  u16* w2T = (u16*)(Fs + 2621440);
  u16* a2T = (u16*)(Fs + 3014656);
  u16* v2T = (u16*)(Fs + 3407872);
  u16* g2T = (u16*)(Fs + 3670016);
  u16* H1b = (u16*)(Fs + 4718592);
  u16* ksc = (u16*)(ws + 88080384);
  u16* asc = (u16*)(ws + 100663296);          // H: asc -> ybuf
  u16* ybuf= (u16*)(ws + 100663296);
  u16* gsc = (u16*)(ws + 113246208);          // I: gsc -> zbuf -> xcm
  u16* zbuf= (u16*)(ws + 113246208);
  u16* xcm = (u16*)(ws + 113246208);
  u16* WbigT = (u16*)(ws + 25165824);         // [24,56M) WkeyT/WvalT
  u16* outG = (u16*)(ws + 125829120);         // J: g bf16
  u16* vsc   = (u16*)d_out;                   // d_out [0,12.6M): v scatter scratch
  u16* WrkvT = ((u16*)d_out) + ME;            // d_out [12.6,37.7M): Wr^T|Wk^T|Wv^T scratch (dead by final GEMM)

  auto GEMM = [&](const u16* a0_, const u16* a1_, const u16* a2_,
                  int amode, int lda_, const u16* bt, int ldb_,
                  void* c0_, void* c1_, void* c2_, int ldc_,
                  int N_, int K_, int em, const float* aux_){
    k_gemm<<<dim3(N_/128, MM/128), 256, 0, stream>>>(a0_,a1_,a2_,amode,lda_,bt,ldb_,c0_,c1_,c2_,ldc_,K_,em,aux_);
  };
  dim3 tb(32,8);

  // 1: LN1 -> xn
  k_lnb<<<MM, 256, 0, stream>>>(x, ln1_w, ln1_b, xn);
  // 2: mixes w,a,v,g
  k_mixA<<<MM, 256, 0, stream>>>(xn, x_w, x_a, x_v, x_g, xw, xa, xv, xg);
  // 3: small-MLP weight prep
  hipMemsetAsync(B1T, 0, 2621440, stream);
  k_tpose<<<dim3(3,64), tb, 0, stream>>>(w1, 2048,  96, B1T + 0*2048,   2048);
  k_tpose<<<dim3(3,64), tb, 0, stream>>>(a1, 2048,  96, B1T + 128*2048, 2048);
  k_tpose<<<dim3(2,64), tb, 0, stream>>>(v1, 2048,  64, B1T + 256*2048, 2048);
  k_tpose<<<dim3(8,64), tb, 0, stream>>>(g1, 2048, 256, B1T + 384*2048, 2048);
  k_tpose<<<dim3(64,3), tb, 0, stream>>>(w2,   96, 2048, w2T,  96);
  k_tpose<<<dim3(64,3), tb, 0, stream>>>(a2,   96, 2048, a2T,  96);
  k_tpose<<<dim3(64,2), tb, 0, stream>>>(v2,   64, 2048, v2T,  64);
  k_tpose<<<dim3(64,8), tb, 0, stream>>>(g2,  256, 2048, g2T, 256);
  // 4: stage-1 MLP GEMMs: (w,a,v) N=384 per-ntile A + fused act; (g) N=256 sigmoid at col+384
  GEMM(xw, xa, xv, 1, 2048, B1T, 2048, H1b, nullptr, nullptr, 640, 384, 2048, 7, nullptr);
  GEMM(xg, xg, xg, 0, 2048, B1T + 384*2048, 2048, H1b, nullptr, nullptr, 640, 256, 2048, 11, nullptr);
  // 5: stage-2 GEMMs
  GEMM(H1b + 0,   H1b, H1b, 0, 640, w2T,  96, decay, nullptr, nullptr, 2048, 2048,  96, 1, w0);
  GEMM(H1b + 128, H1b, H1b, 0, 640, a2T,  96, asc,   nullptr, nullptr, 2048, 2048,  96, 9, a0);
  GEMM(H1b + 256, H1b, H1b, 0, 640, v2T,  64, gsc,   nullptr, nullptr, 2048, 2048,  64, 9, v0);
  GEMM(H1b + 384, H1b, H1b, 0, 640, g2T, 256, outG,  nullptr, nullptr, 2048, 2048, 256, 6, nullptr);
  // 6: mixes r,k
  k_mixB<<<MM, 256, 0, stream>>>(xn, x_r, x_k, xr, xk);
  // 7: merged r|k|v GEMM (N=6144), per-column-group A, scatter to three dests
  k_tpose<<<dim3(64,64), tb, 0, stream>>>(W_r, 2048, 2048, WrkvT,               2048);
  k_tpose<<<dim3(64,64), tb, 0, stream>>>(W_k, 2048, 2048, WrkvT + 2048*2048,   2048);
  k_tpose<<<dim3(64,64), tb, 0, stream>>>(W_v, 2048, 2048, WrkvT + 2*2048*2048, 2048);
  GEMM(xr, xk, xv, 2, 2048, WrkvT, 2048, rsc, ksc, vsc, 2048, 6144, 2048, 10, nullptr);
  // 8: rec prep
  k_make_rec3<<<MM*HH/4, 256, 0, stream>>>(ksc, vsc, asc, gsc, af32, bf32, v_first, k_k, k_a);
  // 9: recurrence -> ybuf
  k_rwkv<<<128, 256, 0, stream>>>(decay, af32, bf32, rsc, ksc, vsc, ybuf);
  // 10: groupnorm + rk*v + gate -> zbuf
  k_gn<<<MM*HH/4, 256, 0, stream>>>(ybuf, rsc, ksc, vsc, r_k, gn_w, gn_b, outG, zbuf);
  // 11: x1 = x + z @ W_o
  k_tpose<<<dim3(64,64), tb, 0, stream>>>(W_o, 2048, 2048, WT, 2048);
  GEMM(zbuf, zbuf, zbuf, 0, 2048, WT, 2048, x1, nullptr, nullptr, 2048, 2048, 2048, 3, x);
  // 12: LN2 -> xn2, mix -> xcm
  k_lnb<<<MM, 256, 0, stream>>>(x1, ln2_w, ln2_b, xn2);
  k_mix1<<<MM, 256, 0, stream>>>(xn2, ffn_x_k, xcm);
  // 13: key GEMM, relu^2 -> kf
  k_tpose<<<dim3(256,64), tb, 0, stream>>>(W_key, 2048, 8192, WbigT, 2048);
  GEMM(xcm, xcm, xcm, 0, 2048, WbigT, 2048, kf, nullptr, nullptr, 8192, 8192, 2048, 4, nullptr);
  // 14: val GEMM -> output 0 (f32)
  k_tpose<<<dim3(64,256), tb, 0, stream>>>(W_val, 8192, 2048, WbigT, 8192);
  GEMM(kf, kf, kf, 0, 8192, WbigT, 8192, outF, nullptr, nullptr, 2048, 2048, 8192, 3, x1);
  // 15: output 1 = v_first passthrough
  hipMemcpyAsync(outF + ME, v_first, ME*sizeof(float), hipMemcpyDeviceToDevice, stream);
}

// Round 13
// 1683.547 us; speedup vs baseline: 2.7637x; 2.7637x over previous
//
#include <hip/hip_runtime.h>
#include <stdint.h>

typedef unsigned short u16;
typedef __attribute__((ext_vector_type(8))) short short8;
typedef __attribute__((ext_vector_type(4))) float f32x4;

#define DEVI __device__ __forceinline__

static constexpr int TT = 768;
static constexpr int CC = 2048;
static constexpr int MM = 3072;
static constexpr int HH = 32;

DEVI float b2f(u16 u){ union{float f; unsigned int i;} x; x.i = ((unsigned int)u)<<16; return x.f; }
DEVI float b2fs(short s){ return b2f((u16)s); }
DEVI u16 f2b(float f){
  unsigned int u = __builtin_bit_cast(unsigned int, f);
  unsigned int r = (u + 0x7fffu + ((u>>16)&1u)) >> 16;
  return (u16)r;
}

DEVI void gload16(const void* g, void* s){
  __builtin_amdgcn_global_load_lds((const __attribute__((address_space(1))) void*)g,
                                   (__attribute__((address_space(3))) void*)s, 16, 0, 0);
}

__global__ __launch_bounds__(256) void k_fillf(float* __restrict__ out, float v, int n){
  for (int i = blockIdx.x*256 + threadIdx.x; i < n; i += gridDim.x*256) out[i] = v;
}

__global__ void k_tpose(const float* __restrict__ src, int R, int Cn, u16* __restrict__ dst, int ldd){
  __shared__ float tile[32][33];
  int c0 = blockIdx.x*32, r0 = blockIdx.y*32;
  #pragma unroll
  for (int i=0;i<4;++i){
    int r = r0 + threadIdx.y + i*8, c = c0 + threadIdx.x;
    tile[threadIdx.y + i*8][threadIdx.x] = (r<R && c<Cn) ? src[(size_t)r*Cn + c] : 0.f;
  }
  __syncthreads();
  #pragma unroll
  for (int i=0;i<4;++i){
    int c = c0 + threadIdx.y + i*8, r = r0 + threadIdx.x;
    if (c<Cn && r<R) dst[(size_t)c*ldd + r] = f2b(tile[threadIdx.x][threadIdx.y + i*8]);
  }
}

__global__ __launch_bounds__(256) void k_lnb(const float* __restrict__ in, const float* __restrict__ w,
                                             const float* __restrict__ bias, u16* __restrict__ out){
  __shared__ float red[8];
  int m = blockIdx.x;
  const float* x = in + (size_t)m*CC;
  float v[8]; float s=0.f, ss=0.f;
  #pragma unroll
  for (int i=0;i<8;++i){ v[i] = x[threadIdx.x + i*256]; s += v[i]; ss += v[i]*v[i]; }
  #pragma unroll
  for (int o=32;o;o>>=1){ s += __shfl_xor(s,o); ss += __shfl_xor(ss,o); }
  int wid = threadIdx.x>>6;
  if ((threadIdx.x&63)==0){ red[wid]=s; red[4+wid]=ss; }
  __syncthreads();
  s  = red[0]+red[1]+red[2]+red[3];
  ss = red[4]+red[5]+red[6]+red[7];
  float mean = s*(1.f/2048.f);
  float var  = ss*(1.f/2048.f) - mean*mean;
  float rstd = rsqrtf(fmaxf(var,0.f) + 1e-5f);
  #pragma unroll
  for (int i=0;i<8;++i){
    int c = threadIdx.x + i*256;
    out[(size_t)m*CC + c] = f2b((v[i]-mean)*rstd*w[c] + bias[c]);
  }
}

__global__ __launch_bounds__(256) void k_mixA(const u16* __restrict__ xn,
  const float* __restrict__ cw, const float* __restrict__ ca, const float* __restrict__ cv,
  const float* __restrict__ cg,
  u16* __restrict__ ow, u16* __restrict__ oa, u16* __restrict__ ov, u16* __restrict__ og)
{
  int m = blockIdx.x; int t = m % TT;
  const u16* cur = xn + (size_t)m*CC;
  const u16* prv = cur - CC;
  bool has = (t>0);
  #pragma unroll
  for (int i=0;i<8;++i){
    int c = threadIdx.x + i*256;
    float xc = b2f(cur[c]);
    float xx = (has ? b2f(prv[c]) : 0.f) - xc;
    size_t o = (size_t)m*CC + c;
    ow[o]=f2b(xc + xx*cw[c]); oa[o]=f2b(xc + xx*ca[c]);
    ov[o]=f2b(xc + xx*cv[c]); og[o]=f2b(xc + xx*cg[c]);
  }
}

__global__ __launch_bounds__(256) void k_mixB(const u16* __restrict__ xn,
  const float* __restrict__ cr, const float* __restrict__ ck,
  u16* __restrict__ orr, u16* __restrict__ ok)
{
  int m = blockIdx.x; int t = m % TT;
  const u16* cur = xn + (size_t)m*CC;
  const u16* prv = cur - CC;
  bool has = (t>0);
  #pragma unroll
  for (int i=0;i<8;++i){
    int c = threadIdx.x + i*256;
    float xc = b2f(cur[c]);
    float xx = (has ? b2f(prv[c]) : 0.f) - xc;
    size_t o = (size_t)m*CC + c;
    orr[o]=f2b(xc + xx*cr[c]); ok[o]=f2b(xc + xx*ck[c]);
  }
}

__global__ __launch_bounds__(256) void k_mix1(const u16* __restrict__ xn, const float* __restrict__ cf,
                                              u16* __restrict__ out){
  int m = blockIdx.x; int t = m % TT;
  const u16* cur = xn + (size_t)m*CC;
  const u16* prv = cur - CC;
  bool has = (t>0);
  #pragma unroll
  for (int i=0;i<8;++i){
    int c = threadIdx.x + i*256;
    float xc = b2f(cur[c]);
    float xx = (has ? b2f(prv[c]) : 0.f) - xc;
    out[(size_t)m*CC + c] = f2b(xc + xx*cf[c]);
  }
}

// ---------------- bf16 MFMA GEMM: 128x128 tile, BK=32, TRI-buffered depth-2 prefetch,
// raw s_barrier + counted vmcnt(4) (loads stay in flight across barriers), XCD swizzle.
// amode: 0 A=A0 | 1 A by ntile (0:A0 1:A1 else:A2) | 2 A by ntile>>4 (0:A0 1:A1 else:A2)
// emode: 0 f32 | 1 decay-scatter f32 | 2 sigmoid bf16 | 3 aux+v f32 | 4 relu^2 bf16
//        5 aux+v bf16 | 6 v bf16 | 7 h1act bf16 | 8 scatter bf16 | 9 sigmoid scatter
//        10 rkv scatter (col>>11 -> C0/C1/C2) | 11 sigmoid bf16 at col+384
__global__ __launch_bounds__(256,2) void k_gemm(
    const u16* A0, const u16* A1, const u16* A2,
    int amode, int lda,
    const u16* __restrict__ BT, int ldb,
    void* C0, void* C1, void* C2, int ldc, int K,
    int emode, const float* __restrict__ aux)
{
  const int tid = threadIdx.x;
  const int w = tid>>6, l = tid&63;

  const int NT = gridDim.x;
  const int nwg = NT * gridDim.y;
  int bid = blockIdx.y * NT + blockIdx.x;
  int qq = nwg >> 3, rr = nwg & 7;
  int xcd = bid & 7, pos = bid >> 3;
  int nid = (xcd < rr ? xcd*(qq+1) : rr*(qq+1) + (xcd-rr)*qq) + pos;
  const int ntile = nid % NT;
  const int mtile = nid / NT;

  const u16* A = A0;
  if (amode==1){ A = (ntile==0)?A0:(ntile==1)?A1:A2; }
  else if (amode==2){ int g = ntile>>4; A = (g==0)?A0:(g==1)?A1:A2; }

  __shared__ __align__(16) u16 As[3*4096];
  __shared__ __align__(16) u16 Bs[3*4096];

  const int sr = w*16 + (l>>2);
  const int sk = (l&3)*8;
  const u16* Ag = A  + (size_t)(mtile*128 + sr)*lda + sk;
  const u16* Bg = BT + (size_t)(ntile*128 + sr)*ldb + sk;
  const size_t a64 = (size_t)64*lda, b64 = (size_t)64*ldb;
  const int wo = w*512;

  const int wm = w>>1, wn = w&1;
  const int fr = l&15, fk = (l>>4)*8;
  const int aoff = (wm*64 + fr)*32 + fk;
  const int boff = (wn*64 + fr)*32 + fk;

  f32x4 acc[4][4];
  const f32x4 zz = {0.f,0.f,0.f,0.f};
  #pragma unroll
  for (int mi=0;mi<4;++mi)
    #pragma unroll
    for (int ni=0;ni<4;++ni) acc[mi][ni] = zz;

  const int nt = K >> 5;

#define STAGE(bufi, k0) do{ \
    u16* dA = As + (bufi)*4096 + wo; \
    u16* dB = Bs + (bufi)*4096 + wo; \
    gload16(Ag + (k0),        dA); \
    gload16(Ag + a64 + (k0),  dA + 2048); \
    gload16(Bg + (k0),        dB); \
    gload16(Bg + b64 + (k0),  dB + 2048); \
  }while(0)

  // prologue: stage tiles 0 and 1 (8 loads in flight)
  STAGE(0, 0);
  if (nt > 1) STAGE(1, 32);

  int cur = 0;
  for (int t=0; t<nt; ++t){
    if (t == nt-1){ asm volatile("s_waitcnt vmcnt(0)" ::: "memory"); }
    else          { asm volatile("s_waitcnt vmcnt(4)" ::: "memory"); }
    __builtin_amdgcn_s_barrier();   // tile t fully in LDS; tile t-1 compute done everywhere
    if (t+2 < nt){
      int nb = cur+2; if (nb>=3) nb-=3;   // buffer of tile t-1, freed by the barrier above
      STAGE(nb, (t+2)<<5);
    }
    const u16* Ab = As + cur*4096;
    const u16* Bb = Bs + cur*4096;
    short8 af[4], bfr[4];
    #pragma unroll
    for (int mi=0;mi<4;++mi) af[mi]  = *(const short8*)(Ab + aoff + mi*512);
    #pragma unroll
    for (int ni=0;ni<4;++ni) bfr[ni] = *(const short8*)(Bb + boff + ni*512);
    #pragma unroll
    for (int mi=0;mi<4;++mi)
      #pragma unroll
      for (int ni=0;ni<4;++ni)
        acc[mi][ni] = __builtin_amdgcn_mfma_f32_16x16x32_bf16(af[mi], bfr[ni], acc[mi][ni], 0,0,0);
    cur = (cur+1==3)?0:cur+1;
  }
#undef STAGE

  const int rb0 = mtile*128 + wm*64 + (l>>4)*4;
  const int cb0 = ntile*128 + wn*64 + fr;
  #pragma unroll
  for (int mi=0;mi<4;++mi){
    #pragma unroll
    for (int ni=0;ni<4;++ni){
      #pragma unroll
      for (int q2=0;q2<4;++q2){
        int row = rb0 + mi*16 + q2;
        int col = cb0 + ni*16;
        float v = acc[mi][ni][q2];
        if (emode==0){
          ((float*)C0)[(size_t)row*ldc + col] = v;
        } else if (emode==1){
          float valw = aux[col] + v;
          float zneg = -valw;
          float sp = (zneg > 20.f) ? zneg : log1pf(expf(zneg));
          float wlog = -sp - 0.5f;
          float dec = expf(-expf(wlog));
          int b_ = row/TT, t_ = row - b_*TT;
          int h_ = col>>6, n_ = col&63;
          ((float*)C0)[((size_t)(b_*HH + h_)*TT + t_)*64 + n_] = dec;
        } else if (emode==2){
          float s = 1.f/(1.f+expf(-(aux[col]+v)));
          ((u16*)C0)[(size_t)row*ldc + col] = f2b(s);
        } else if (emode==3){
          ((float*)C0)[(size_t)row*ldc + col] = aux[(size_t)row*ldc + col] + v;
        } else if (emode==4){
          float r_ = fmaxf(v, 0.f);
          ((u16*)C0)[(size_t)row*ldc + col] = f2b(r_*r_);
        } else if (emode==5){
          ((u16*)C0)[(size_t)row*ldc + col] = f2b(aux[(size_t)row*ldc + col] + v);
        } else if (emode==6){
          ((u16*)C0)[(size_t)row*ldc + col] = f2b(v);
        } else if (emode==7){
          float r_ = v;
          if (col < 128) r_ = tanhf(v);
          else if (col >= 384) r_ = 1.f/(1.f+expf(-v));
          ((u16*)C0)[(size_t)row*ldc + col] = f2b(r_);
        } else if (emode==8){
          int b_ = row/TT, t_ = row - b_*TT;
          int h_ = col>>6, n_ = col&63;
          ((u16*)C0)[((size_t)(b_*HH + h_)*TT + t_)*64 + n_] = f2b(v);
        } else if (emode==9){
          float s = 1.f/(1.f+expf(-(aux[col]+v)));
          int b_ = row/TT, t_ = row - b_*TT;
          int h_ = col>>6, n_ = col&63;
          ((u16*)C0)[((size_t)(b_*HH + h_)*TT + t_)*64 + n_] = f2b(s);
        } else if (emode==10){
          int g = col>>11, c2 = col&2047;
          int b_ = row/TT, t_ = row - b_*TT;
          int h_ = c2>>6, n_ = c2&63;
          u16* dst = (g==0)?(u16*)C0:(g==1)?(u16*)C1:(u16*)C2;
          dst[((size_t)(b_*HH + h_)*TT + t_)*64 + n_] = f2b(v);
        } else { // 11
          float s = 1.f/(1.f+expf(-v));
          ((u16*)C0)[(size_t)row*ldc + (col+384)] = f2b(s);
        }
      }
    }
  }
}

__global__ __launch_bounds__(256) void k_make_rec3(
  u16* __restrict__ ksc, u16* __restrict__ vsc,
  const u16* __restrict__ asc, const u16* __restrict__ gsc,
  float* __restrict__ af, float* __restrict__ bf,
  const float* __restrict__ v_first, const float* __restrict__ k_k, const float* __restrict__ k_a)
{
  int idx = blockIdx.x*4 + (threadIdx.x>>6);
  int l = threadIdx.x & 63;
  int bh = idx / TT, t = idx - bh*TT;
  int b = bh >> 5, h = bh & 31;
  int c = h*64 + l;
  size_t off = (size_t)idx*64 + l;
  size_t mo = ((size_t)b*TT + t)*CC + c;
  float kq = b2f(ksc[off]);
  float vv = b2f(vsc[off]);
  float aa = b2f(asc[off]);
  float sg = b2f(gsc[off]);
  float vf = v_first[mo];
  float kkr = kq * k_k[c];
  float s2 = kkr*kkr;
  #pragma unroll
  for (int o=32;o;o>>=1) s2 += __shfl_xor(s2,o);
  float kk = kkr / fmaxf(sqrtf(s2), 1e-12f);
  ksc[off] = f2b(kq*(1.f + (aa-1.f)*k_a[c]));
  vsc[off] = f2b(vv + (vf-vv)*sg);
  af[off] = -kk;
  bf[off] = kk*aa;
}

struct StepB { f32x4 d[4]; f32x4 a[4]; f32x4 b[4]; short8 r[2], k[2]; float vi; };

DEVI void loadStep(StepB& sb, const float* __restrict__ dP, const float* __restrict__ aP,
                   const float* __restrict__ bP, const u16* __restrict__ rP,
                   const u16* __restrict__ kP, const u16* __restrict__ vP,
                   size_t off, size_t voff){
  const float* dp = dP + off;
  const float* ap = aP + off;
  const float* bp = bP + off;
  #pragma unroll
  for (int q=0;q<4;++q){
    sb.d[q] = *(const f32x4*)(dp+4*q);
    sb.a[q] = *(const f32x4*)(ap+4*q);
    sb.b[q] = *(const f32x4*)(bp+4*q);
  }
  const short8* rp = (const short8*)(rP + off);
  const short8* kp = (const short8*)(kP + off);
  sb.r[0]=rp[0]; sb.r[1]=rp[1];
  sb.k[0]=kp[0]; sb.k[1]=kp[1];
  sb.vi = b2f(vP[voff]);
}

DEVI float stepCompute(const StepB& sb, float S[16]){
  float sa = 0.f;
  #pragma unroll
  for (int q=0;q<16;++q) sa += S[q]*sb.a[q>>2][q&3];
  sa += __shfl_xor(sa,16); sa += __shfl_xor(sa,32);
  float yv = 0.f;
  #pragma unroll
  for (int q=0;q<16;++q){
    float Sq = S[q]*sb.d[q>>2][q&3] + sa*sb.b[q>>2][q&3] + sb.vi*b2fs(sb.k[q>>3][q&7]);
    S[q] = Sq;
    yv += Sq*b2fs(sb.r[q>>3][q&7]);
  }
  yv += __shfl_xor(yv,16); yv += __shfl_xor(yv,32);
  return yv;
}

__global__ __launch_bounds__(256,1) void k_rwkv(
    const float* __restrict__ decay, const float* __restrict__ af, const float* __restrict__ bf,
    const u16* __restrict__ rb, const u16* __restrict__ kb, const u16* __restrict__ vb,
    u16* __restrict__ y)
{
  int bh = blockIdx.x;
  int b = bh>>5, h = bh&31;
  int tid = threadIdx.x, w = tid>>6, l = tid&63;
  int i = w*16 + (l&15);
  int cch = l>>4;
  int j0 = cch*16;
  const size_t base = (size_t)bh * (TT*64);
  float S[16];
  #pragma unroll
  for (int q=0;q<16;++q) S[q]=0.f;

  size_t yb = (size_t)b*TT*CC + h*64 + i;
  StepB sA, sB;
  loadStep(sA, decay, af, bf, rb, kb, vb, base + j0, base + i);
  for (int t=0;t<TT;t+=2){
    loadStep(sB, decay, af, bf, rb, kb, vb, base + (size_t)(t+1)*64 + j0, base + (size_t)(t+1)*64 + i);
    float y0 = stepCompute(sA, S);
    if (cch==0) y[yb + (size_t)t*CC] = f2b(y0);
    if (t+2 < TT)
      loadStep(sA, decay, af, bf, rb, kb, vb, base + (size_t)(t+2)*64 + j0, base + (size_t)(t+2)*64 + i);
    float y1 = stepCompute(sB, S);
    if (cch==0) y[yb + (size_t)(t+1)*CC] = f2b(y1);
  }
}

__global__ __launch_bounds__(256) void k_gn(
  const u16* __restrict__ y, const u16* __restrict__ rb, const u16* __restrict__ kb,
  const u16* __restrict__ vb, const float* __restrict__ r_k,
  const float* __restrict__ gnw, const float* __restrict__ gnb,
  const u16* __restrict__ gg, u16* __restrict__ z)
{
  int idx = blockIdx.x*4 + (threadIdx.x>>6);
  int l = threadIdx.x&63;
  int m = idx>>5, h = idx&31;
  int c = h*64 + l;
  size_t mo = (size_t)m*CC + c;
  float yv = b2f(y[mo]);
  float s = yv;
  #pragma unroll
  for (int o=32;o;o>>=1) s += __shfl_xor(s,o);
  float mean = s*(1.f/64.f);
  float dv = yv - mean;
  float vs = dv*dv;
  #pragma unroll
  for (int o=32;o;o>>=1) vs += __shfl_xor(vs,o);
  float gn = dv*rsqrtf(vs*(1.f/64.f) + 6.4e-4f)*gnw[c] + gnb[c];
  size_t ro = ((size_t)((m/TT)*HH + h)*TT + (m%TT))*64 + l;
  float rv=b2f(rb[ro]), kv=b2f(kb[ro]), vv=b2f(vb[ro]);
  float p = rv*kv*r_k[c];
  #pragma unroll
  for (int o=32;o;o>>=1) p += __shfl_xor(p,o);
  z[mo] = f2b((gn + p*vv)*b2f(gg[mo]));
}

extern "C" void kernel_launch(void* const* d_in, const int* in_sizes, int n_in,
                              void* d_out, int out_size, void* d_ws, size_t ws_size,
                              hipStream_t stream)
{
  (void)out_size;
  const float* x      = (const float*)d_in[0];
  const float* v_first= (const float*)d_in[1];
  const float* ln1_w  = (const float*)d_in[2];
  const float* ln1_b  = (const float*)d_in[3];
  const float* ln2_w  = (const float*)d_in[4];
  const float* ln2_b  = (const float*)d_in[5];
  const float* x_r    = (const float*)d_in[6];
  const float* x_w    = (const float*)d_in[7];
  const float* x_k    = (const float*)d_in[8];
  const float* x_v    = (const float*)d_in[9];
  const float* x_a    = (const float*)d_in[10];
  const float* x_g    = (const float*)d_in[11];
  const float* w0     = (const float*)d_in[12];
  const float* w1     = (const float*)d_in[13];
  const float* w2     = (const float*)d_in[14];
  const float* a0     = (const float*)d_in[15];
  const float* a1     = (const float*)d_in[16];
  const float* a2     = (const float*)d_in[17];
  const float* v0     = (const float*)d_in[18];
  const float* v1     = (const float*)d_in[19];
  const float* v2     = (const float*)d_in[20];
  const float* g1     = (const float*)d_in[21];
  const float* g2     = (const float*)d_in[22];
  const float* k_k    = (const float*)d_in[23];
  const float* k_a    = (const float*)d_in[24];
  const float* r_k    = (const float*)d_in[25];
  const float* W_r    = (const float*)d_in[26];
  const float* W_k    = (const float*)d_in[27];
  const float* W_v    = (const float*)d_in[28];
  const float* W_o    = (const float*)d_in[29];
  const float* gn_w   = (const float*)d_in[30];
  const float* gn_b   = (const float*)d_in[31];
  const float* ffn_x_k= (const float*)d_in[32];
  const float* W_key  = (const float*)d_in[33];
  const float* W_val  = (const float*)d_in[34];

  const size_t ME = (size_t)MM*CC;
  float* outF = (float*)d_out;

  bool ok = (n_in==35)
    && in_sizes[0]==6291456 && in_sizes[1]==6291456 && in_sizes[2]==2048
    && in_sizes[12]==2048 && in_sizes[13]==196608 && in_sizes[14]==196608
    && in_sizes[16]==196608 && in_sizes[19]==131072 && in_sizes[21]==524288
    && in_sizes[25]==2048 && in_sizes[26]==4194304 && in_sizes[33]==16777216
    && in_sizes[34]==16777216;
  if (!ok){
    k_fillf<<<2048, 256, 0, stream>>>(outF, 1099511627776.f, (int)ME);
    return;
  }

  constexpr size_t WS_NEED = 125829120 + 12582912;
  if (ws_size < WS_NEED){
    k_fillf<<<2048, 256, 0, stream>>>(outF, (float)(1u<<21) * (float)(ws_size>>20), (int)ME);
    return;
  }
  char* ws = (char*)d_ws;
  float* decay = (float*)(ws + 0);
  float* x1    = (float*)(ws + 0);
  u16* xn   = (u16*)(ws + 25165824);
  u16* WT   = (u16*)(ws + 25165824);
  float* bf32 = (float*)(ws + 25165824);
  u16* xw  = (u16*)(ws + 37748736);
  u16* xr  = (u16*)(ws + 37748736);
  u16* xn2 = (u16*)(ws + 37748736);
  float* af32 = (float*)(ws + 50331648);
  u16* xa  = (u16*)(ws + 50331648);
  u16* xk  = (u16*)(ws + 50331648);
  u16* xv  = (u16*)(ws + 62914560);
  u16* kf  = (u16*)(ws + 62914560);
  u16* xg  = (u16*)(ws + 75497472);
  u16* rsc = (u16*)(ws + 75497472);
  char* Fs = ws + 88080384;
  u16* B1T = (u16*)(Fs);
  u16* w2T = (u16*)(Fs + 2621440);
  u16* a2T = (u16*)(Fs + 3014656);
  u16* v2T = (u16*)(Fs + 3407872);
  u16* g2T = (u16*)(Fs + 3670016);
  u16* H1b = (u16*)(Fs + 4718592);
  u16* ksc = (u16*)(ws + 88080384);
  u16* asc = (u16*)(ws + 100663296);
  u16* ybuf= (u16*)(ws + 100663296);
  u16* gsc = (u16*)(ws + 113246208);
  u16* zbuf= (u16*)(ws + 113246208);
  u16* xcm = (u16*)(ws + 113246208);
  u16* WbigT = (u16*)(ws + 25165824);
  u16* outG = (u16*)(ws + 125829120);
  u16* vsc   = (u16*)d_out;
  u16* WrkvT = ((u16*)d_out) + ME;

  auto GEMM = [&](const u16* a0_, const u16* a1_, const u16* a2_,
                  int amode, int lda_, const u16* bt, int ldb_,
                  void* c0_, void* c1_, void* c2_, int ldc_,
                  int N_, int K_, int em, const float* aux_){
    k_gemm<<<dim3(N_/128, MM/128), 256, 0, stream>>>(a0_,a1_,a2_,amode,lda_,bt,ldb_,c0_,c1_,c2_,ldc_,K_,em,aux_);
  };
  dim3 tb(32,8);

  k_lnb<<<MM, 256, 0, stream>>>(x, ln1_w, ln1_b, xn);
  k_mixA<<<MM, 256, 0, stream>>>(xn, x_w, x_a, x_v, x_g, xw, xa, xv, xg);
  hipMemsetAsync(B1T, 0, 2621440, stream);
  k_tpose<<<dim3(3,64), tb, 0, stream>>>(w1, 2048,  96, B1T + 0*2048,   2048);
  k_tpose<<<dim3(3,64), tb, 0, stream>>>(a1, 2048,  96, B1T + 128*2048, 2048);
  k_tpose<<<dim3(2,64), tb, 0, stream>>>(v1, 2048,  64, B1T + 256*2048, 2048);
  k_tpose<<<dim3(8,64), tb, 0, stream>>>(g1, 2048, 256, B1T + 384*2048, 2048);
  k_tpose<<<dim3(64,3), tb, 0, stream>>>(w2,   96, 2048, w2T,  96);
  k_tpose<<<dim3(64,3), tb, 0, stream>>>(a2,   96, 2048, a2T,  96);
  k_tpose<<<dim3(64,2), tb, 0, stream>>>(v2,   64, 2048, v2T,  64);
  k_tpose<<<dim3(64,8), tb, 0, stream>>>(g2,  256, 2048, g2T, 256);
  GEMM(xw, xa, xv, 1, 2048, B1T, 2048, H1b, nullptr, nullptr, 640, 384, 2048, 7, nullptr);
  GEMM(xg, xg, xg, 0, 2048, B1T + 384*2048, 2048, H1b, nullptr, nullptr, 640, 256, 2048, 11, nullptr);
  GEMM(H1b + 0,   H1b, H1b, 0, 640, w2T,  96, decay, nullptr, nullptr, 2048, 2048,  96, 1, w0);
  GEMM(H1b + 128, H1b, H1b, 0, 640, a2T,  96, asc,   nullptr, nullptr, 2048, 2048,  96, 9, a0);
  GEMM(H1b + 256, H1b, H1b, 0, 640, v2T,  64, gsc,   nullptr, nullptr, 2048, 2048,  64, 9, v0);
  GEMM(H1b + 384, H1b, H1b, 0, 640, g2T, 256, outG,  nullptr, nullptr, 2048, 2048, 256, 6, nullptr);
  k_mixB<<<MM, 256, 0, stream>>>(xn, x_r, x_k, xr, xk);
  k_tpose<<<dim3(64,64), tb, 0, stream>>>(W_r, 2048, 2048, WrkvT,               2048);
  k_tpose<<<dim3(64,64), tb, 0, stream>>>(W_k, 2048, 2048, WrkvT + 2048*2048,   2048);
  k_tpose<<<dim3(64,64), tb, 0, stream>>>(W_v, 2048, 2048, WrkvT + 2*2048*2048, 2048);
  GEMM(xr, xk, xv, 2, 2048, WrkvT, 2048, rsc, ksc, vsc, 2048, 6144, 2048, 10, nullptr);
  k_make_rec3<<<MM*HH/4, 256, 0, stream>>>(ksc, vsc, asc, gsc, af32, bf32, v_first, k_k, k_a);
  k_rwkv<<<128, 256, 0, stream>>>(decay, af32, bf32, rsc, ksc, vsc, ybuf);
  k_gn<<<MM*HH/4, 256, 0, stream>>>(ybuf, rsc, ksc, vsc, r_k, gn_w, gn_b, outG, zbuf);
  k_tpose<<<dim3(64,64), tb, 0, stream>>>(W_o, 2048, 2048, WT, 2048);
  GEMM(zbuf, zbuf, zbuf, 0, 2048, WT, 2048, x1, nullptr, nullptr, 2048, 2048, 2048, 3, x);
  k_lnb<<<MM, 256, 0, stream>>>(x1, ln2_w, ln2_b, xn2);
  k_mix1<<<MM, 256, 0, stream>>>(xn2, ffn_x_k, xcm);
  k_tpose<<<dim3(256,64), tb, 0, stream>>>(W_key, 2048, 8192, WbigT, 2048);
  GEMM(xcm, xcm, xcm, 0, 2048, WbigT, 2048, kf, nullptr, nullptr, 8192, 8192, 2048, 4, nullptr);
  k_tpose<<<dim3(64,256), tb, 0, stream>>>(W_val, 8192, 2048, WbigT, 8192);
  GEMM(kf, kf, kf, 0, 8192, WbigT, 8192, outF, nullptr, nullptr, 2048, 2048, 8192, 3, x1);
  hipMemcpyAsync(outF + ME, v_first, ME*sizeof(float), hipMemcpyDeviceToDevice, stream);
}

// Round 14
// 1551.081 us; speedup vs baseline: 2.9998x; 1.0854x over previous
//
#include <hip/hip_runtime.h>
#include <stdint.h>

typedef unsigned short u16;
typedef __attribute__((ext_vector_type(8))) short short8;
typedef __attribute__((ext_vector_type(4))) float f32x4;

#define DEVI __device__ __forceinline__

static constexpr int TT = 768;
static constexpr int CC = 2048;
static constexpr int MM = 3072;
static constexpr int HH = 32;

DEVI float b2f(u16 u){ union{float f; unsigned int i;} x; x.i = ((unsigned int)u)<<16; return x.f; }
DEVI float b2fs(short s){ return b2f((u16)s); }
DEVI u16 f2b(float f){
  unsigned int u = __builtin_bit_cast(unsigned int, f);
  unsigned int r = (u + 0x7fffu + ((u>>16)&1u)) >> 16;
  return (u16)r;
}

DEVI void gload16(const void* g, void* s){
  __builtin_amdgcn_global_load_lds((const __attribute__((address_space(1))) void*)g,
                                   (__attribute__((address_space(3))) void*)s, 16, 0, 0);
}

__global__ __launch_bounds__(256) void k_fillf(float* __restrict__ out, float v, int n){
  for (int i = blockIdx.x*256 + threadIdx.x; i < n; i += gridDim.x*256) out[i] = v;
}

__global__ void k_tpose(const float* __restrict__ src, int R, int Cn, u16* __restrict__ dst, int ldd){
  __shared__ float tile[32][33];
  int c0 = blockIdx.x*32, r0 = blockIdx.y*32;
  #pragma unroll
  for (int i=0;i<4;++i){
    int r = r0 + threadIdx.y + i*8, c = c0 + threadIdx.x;
    tile[threadIdx.y + i*8][threadIdx.x] = (r<R && c<Cn) ? src[(size_t)r*Cn + c] : 0.f;
  }
  __syncthreads();
  #pragma unroll
  for (int i=0;i<4;++i){
    int c = c0 + threadIdx.y + i*8, r = r0 + threadIdx.x;
    if (c<Cn && r<R) dst[(size_t)c*ldd + r] = f2b(tile[threadIdx.x][threadIdx.y + i*8]);
  }
}

__global__ __launch_bounds__(256) void k_lnb(const float* __restrict__ in, const float* __restrict__ w,
                                             const float* __restrict__ bias, u16* __restrict__ out){
  __shared__ float red[8];
  int m = blockIdx.x;
  const float* x = in + (size_t)m*CC;
  float v[8]; float s=0.f, ss=0.f;
  #pragma unroll
  for (int i=0;i<8;++i){ v[i] = x[threadIdx.x + i*256]; s += v[i]; ss += v[i]*v[i]; }
  #pragma unroll
  for (int o=32;o;o>>=1){ s += __shfl_xor(s,o); ss += __shfl_xor(ss,o); }
  int wid = threadIdx.x>>6;
  if ((threadIdx.x&63)==0){ red[wid]=s; red[4+wid]=ss; }
  __syncthreads();
  s  = red[0]+red[1]+red[2]+red[3];
  ss = red[4]+red[5]+red[6]+red[7];
  float mean = s*(1.f/2048.f);
  float var  = ss*(1.f/2048.f) - mean*mean;
  float rstd = rsqrtf(fmaxf(var,0.f) + 1e-5f);
  #pragma unroll
  for (int i=0;i<8;++i){
    int c = threadIdx.x + i*256;
    out[(size_t)m*CC + c] = f2b((v[i]-mean)*rstd*w[c] + bias[c]);
  }
}

__global__ __launch_bounds__(256) void k_mixA(const u16* __restrict__ xn,
  const float* __restrict__ cw, const float* __restrict__ ca, const float* __restrict__ cv,
  const float* __restrict__ cg,
  u16* __restrict__ ow, u16* __restrict__ oa, u16* __restrict__ ov, u16* __restrict__ og)
{
  int m = blockIdx.x; int t = m % TT;
  const u16* cur = xn + (size_t)m*CC;
  const u16* prv = cur - CC;
  bool has = (t>0);
  #pragma unroll
  for (int i=0;i<8;++i){
    int c = threadIdx.x + i*256;
    float xc = b2f(cur[c]);
    float xx = (has ? b2f(prv[c]) : 0.f) - xc;
    size_t o = (size_t)m*CC + c;
    ow[o]=f2b(xc + xx*cw[c]); oa[o]=f2b(xc + xx*ca[c]);
    ov[o]=f2b(xc + xx*cv[c]); og[o]=f2b(xc + xx*cg[c]);
  }
}

__global__ __launch_bounds__(256) void k_mixB(const u16* __restrict__ xn,
  const float* __restrict__ cr, const float* __restrict__ ck,
  u16* __restrict__ orr, u16* __restrict__ ok)
{
  int m = blockIdx.x; int t = m % TT;
  const u16* cur = xn + (size_t)m*CC;
  const u16* prv = cur - CC;
  bool has = (t>0);
  #pragma unroll
  for (int i=0;i<8;++i){
    int c = threadIdx.x + i*256;
    float xc = b2f(cur[c]);
    float xx = (has ? b2f(prv[c]) : 0.f) - xc;
    size_t o = (size_t)m*CC + c;
    orr[o]=f2b(xc + xx*cr[c]); ok[o]=f2b(xc + xx*ck[c]);
  }
}

__global__ __launch_bounds__(256) void k_mix1(const u16* __restrict__ xn, const float* __restrict__ cf,
                                              u16* __restrict__ out){
  int m = blockIdx.x; int t = m % TT;
  const u16* cur = xn + (size_t)m*CC;
  const u16* prv = cur - CC;
  bool has = (t>0);
  #pragma unroll
  for (int i=0;i<8;++i){
    int c = threadIdx.x + i*256;
    float xc = b2f(cur[c]);
    float xx = (has ? b2f(prv[c]) : 0.f) - xc;
    out[(size_t)m*CC + c] = f2b(xc + xx*cf[c]);
  }
}

// ---------------- bf16 MFMA GEMM: 128x128 tile, BK=32, TRI-buffered depth-2 prefetch,
// raw s_barrier + counted vmcnt(4), XCD swizzle.  (unchanged from r13 — proven)
__global__ __launch_bounds__(256,2) void k_gemm(
    const u16* A0, const u16* A1, const u16* A2,
    int amode, int lda,
    const u16* __restrict__ BT, int ldb,
    void* C0, void* C1, void* C2, int ldc, int K,
    int emode, const float* __restrict__ aux)
{
  const int tid = threadIdx.x;
  const int w = tid>>6, l = tid&63;

  const int NT = gridDim.x;
  const int nwg = NT * gridDim.y;
  int bid = blockIdx.y * NT + blockIdx.x;
  int qq = nwg >> 3, rr = nwg & 7;
  int xcd = bid & 7, pos = bid >> 3;
  int nid = (xcd < rr ? xcd*(qq+1) : rr*(qq+1) + (xcd-rr)*qq) + pos;
  const int ntile = nid % NT;
  const int mtile = nid / NT;

  const u16* A = A0;
  if (amode==1){ A = (ntile==0)?A0:(ntile==1)?A1:A2; }
  else if (amode==2){ int g = ntile>>4; A = (g==0)?A0:(g==1)?A1:A2; }

  __shared__ __align__(16) u16 As[3*4096];
  __shared__ __align__(16) u16 Bs[3*4096];

  const int sr = w*16 + (l>>2);
  const int sk = (l&3)*8;
  const u16* Ag = A  + (size_t)(mtile*128 + sr)*lda + sk;
  const u16* Bg = BT + (size_t)(ntile*128 + sr)*ldb + sk;
  const size_t a64 = (size_t)64*lda, b64 = (size_t)64*ldb;
  const int wo = w*512;

  const int wm = w>>1, wn = w&1;
  const int fr = l&15, fk = (l>>4)*8;
  const int aoff = (wm*64 + fr)*32 + fk;
  const int boff = (wn*64 + fr)*32 + fk;

  f32x4 acc[4][4];
  const f32x4 zz = {0.f,0.f,0.f,0.f};
  #pragma unroll
  for (int mi=0;mi<4;++mi)
    #pragma unroll
    for (int ni=0;ni<4;++ni) acc[mi][ni] = zz;

  const int nt = K >> 5;

#define STAGE(bufi, k0) do{ \
    u16* dA = As + (bufi)*4096 + wo; \
    u16* dB = Bs + (bufi)*4096 + wo; \
    gload16(Ag + (k0),        dA); \
    gload16(Ag + a64 + (k0),  dA + 2048); \
    gload16(Bg + (k0),        dB); \
    gload16(Bg + b64 + (k0),  dB + 2048); \
  }while(0)

  STAGE(0, 0);
  if (nt > 1) STAGE(1, 32);

  int cur = 0;
  for (int t=0; t<nt; ++t){
    if (t == nt-1){ asm volatile("s_waitcnt vmcnt(0)" ::: "memory"); }
    else          { asm volatile("s_waitcnt vmcnt(4)" ::: "memory"); }
    __builtin_amdgcn_s_barrier();
    if (t+2 < nt){
      int nb = cur+2; if (nb>=3) nb-=3;
      STAGE(nb, (t+2)<<5);
    }
    const u16* Ab = As + cur*4096;
    const u16* Bb = Bs + cur*4096;
    short8 af[4], bfr[4];
    #pragma unroll
    for (int mi=0;mi<4;++mi) af[mi]  = *(const short8*)(Ab + aoff + mi*512);
    #pragma unroll
    for (int ni=0;ni<4;++ni) bfr[ni] = *(const short8*)(Bb + boff + ni*512);
    #pragma unroll
    for (int mi=0;mi<4;++mi)
      #pragma unroll
      for (int ni=0;ni<4;++ni)
        acc[mi][ni] = __builtin_amdgcn_mfma_f32_16x16x32_bf16(af[mi], bfr[ni], acc[mi][ni], 0,0,0);
    cur = (cur+1==3)?0:cur+1;
  }
#undef STAGE

  const int rb0 = mtile*128 + wm*64 + (l>>4)*4;
  const int cb0 = ntile*128 + wn*64 + fr;
  #pragma unroll
  for (int mi=0;mi<4;++mi){
    #pragma unroll
    for (int ni=0;ni<4;++ni){
      #pragma unroll
      for (int q2=0;q2<4;++q2){
        int row = rb0 + mi*16 + q2;
        int col = cb0 + ni*16;
        float v = acc[mi][ni][q2];
        if (emode==0){
          ((float*)C0)[(size_t)row*ldc + col] = v;
        } else if (emode==1){
          float valw = aux[col] + v;
          float zneg = -valw;
          float sp = (zneg > 20.f) ? zneg : log1pf(expf(zneg));
          float wlog = -sp - 0.5f;
          float dec = expf(-expf(wlog));
          int b_ = row/TT, t_ = row - b_*TT;
          int h_ = col>>6, n_ = col&63;
          ((float*)C0)[((size_t)(b_*HH + h_)*TT + t_)*64 + n_] = dec;
        } else if (emode==2){
          float s = 1.f/(1.f+expf(-(aux[col]+v)));
          ((u16*)C0)[(size_t)row*ldc + col] = f2b(s);
        } else if (emode==3){
          ((float*)C0)[(size_t)row*ldc + col] = aux[(size_t)row*ldc + col] + v;
        } else if (emode==4){
          float r_ = fmaxf(v, 0.f);
          ((u16*)C0)[(size_t)row*ldc + col] = f2b(r_*r_);
        } else if (emode==5){
          ((u16*)C0)[(size_t)row*ldc + col] = f2b(aux[(size_t)row*ldc + col] + v);
        } else if (emode==6){
          ((u16*)C0)[(size_t)row*ldc + col] = f2b(v);
        } else if (emode==7){
          float r_ = v;
          if (col < 128) r_ = tanhf(v);
          else if (col >= 384) r_ = 1.f/(1.f+expf(-v));
          ((u16*)C0)[(size_t)row*ldc + col] = f2b(r_);
        } else if (emode==8){
          int b_ = row/TT, t_ = row - b_*TT;
          int h_ = col>>6, n_ = col&63;
          ((u16*)C0)[((size_t)(b_*HH + h_)*TT + t_)*64 + n_] = f2b(v);
        } else if (emode==9){
          float s = 1.f/(1.f+expf(-(aux[col]+v)));
          int b_ = row/TT, t_ = row - b_*TT;
          int h_ = col>>6, n_ = col&63;
          ((u16*)C0)[((size_t)(b_*HH + h_)*TT + t_)*64 + n_] = f2b(s);
        } else if (emode==10){
          int g = col>>11, c2 = col&2047;
          int b_ = row/TT, t_ = row - b_*TT;
          int h_ = c2>>6, n_ = c2&63;
          u16* dst = (g==0)?(u16*)C0:(g==1)?(u16*)C1:(u16*)C2;
          dst[((size_t)(b_*HH + h_)*TT + t_)*64 + n_] = f2b(v);
        } else { // 11
          float s = 1.f/(1.f+expf(-v));
          ((u16*)C0)[(size_t)row*ldc + (col+384)] = f2b(s);
        }
      }
    }
  }
}

__global__ __launch_bounds__(256) void k_make_rec3(
  u16* __restrict__ ksc, u16* __restrict__ vsc,
  const u16* __restrict__ asc, const u16* __restrict__ gsc,
  float* __restrict__ af, float* __restrict__ bf,
  const float* __restrict__ v_first, const float* __restrict__ k_k, const float* __restrict__ k_a)
{
  int idx = blockIdx.x*4 + (threadIdx.x>>6);
  int l = threadIdx.x & 63;
  int bh = idx / TT, t = idx - bh*TT;
  int b = bh >> 5, h = bh & 31;
  int c = h*64 + l;
  size_t off = (size_t)idx*64 + l;
  size_t mo = ((size_t)b*TT + t)*CC + c;
  float kq = b2f(ksc[off]);
  float vv = b2f(vsc[off]);
  float aa = b2f(asc[off]);
  float sg = b2f(gsc[off]);
  float vf = v_first[mo];
  float kkr = kq * k_k[c];
  float s2 = kkr*kkr;
  #pragma unroll
  for (int o=32;o;o>>=1) s2 += __shfl_xor(s2,o);
  float kk = kkr / fmaxf(sqrtf(s2), 1e-12f);
  ksc[off] = f2b(kq*(1.f + (aa-1.f)*k_a[c]));
  vsc[off] = f2b(vv + (vf-vv)*sg);
  af[off] = -kk;
  bf[off] = kk*aa;
}

// ---------------- RWKV7 recurrence: LDS-staged 16-step chunks, tri-buffered,
// counted vmcnt(6) + raw s_barrier (same recipe as k_gemm).
// Block per (b,h): 4 waves; wave w owns state rows [w*16,w*16+16); lane layout as before.
static constexpr int RCH = 16;                 // steps per chunk
static constexpr int RNC = TT / RCH;           // 48 chunks
static constexpr int RBUF = 18432;             // bytes per chunk buffer

__global__ __launch_bounds__(256,1) void k_rwkv(
    const float* __restrict__ decay, const float* __restrict__ af, const float* __restrict__ bf,
    const u16* __restrict__ rb, const u16* __restrict__ kb, const u16* __restrict__ vb,
    u16* __restrict__ y)
{
  __shared__ __align__(16) char lds[3*RBUF];   // 54 KB: {d,a,b f32 | r,k,v bf16} x 3
  int bh = blockIdx.x;
  int b = bh>>5, h = bh&31;
  int tid = threadIdx.x, w = tid>>6, l = tid&63;
  int i = w*16 + (l&15);
  int j0 = (l>>4)*16;
  const size_t base = (size_t)bh * (TT*64);

  const float* dB = decay + base;
  const float* aB = af + base;
  const float* bB = bf + base;
  const u16*  rB = rb + base;
  const u16*  kB = kb + base;
  const u16*  vB = vb + base;

  float S[16];
  #pragma unroll
  for (int q=0;q<16;++q) S[q]=0.f;
  float ycur[RCH], yprev[RCH];
  size_t yb = (size_t)b*TT*CC + h*64 + i;

  // staging thread roles
  const int fe = tid*4;                 // f32 element index (one f32x4 per thread)
  const int he = w*256 + l*8;           // u16 element index (lanes 0-31 per wave)
  const bool hlo = (l < 32);

#define RSTAGE(bufi, c) do{ \
    char* bs = lds + (bufi)*RBUF; \
    size_t cb = (size_t)(c)*1024; \
    gload16(dB + cb + fe, bs + tid*16); \
    gload16(aB + cb + fe, bs + 4096 + tid*16); \
    gload16(bB + cb + fe, bs + 8192 + tid*16); \
    if (hlo){ \
      gload16(rB + cb + he, bs + 12288 + w*512 + l*16); \
      gload16(kB + cb + he, bs + 14336 + w*512 + l*16); \
      gload16(vB + cb + he, bs + 16384 + w*512 + l*16); \
    } \
  }while(0)

  RSTAGE(0, 0);
  RSTAGE(1, 1);

  int cur = 0;
  for (int c=0; c<RNC; ++c){
    if (c == RNC-1){ asm volatile("s_waitcnt vmcnt(0)" ::: "memory"); }
    else           { asm volatile("s_waitcnt vmcnt(6)" ::: "memory"); }
    __builtin_amdgcn_s_barrier();
    // store previous chunk's y (before staging, so vmcnt(6) keeps only next-chunk loads in flight)
    if (c > 0){
      int t0 = (c-1)*RCH;
      #pragma unroll
      for (int s=0;s<RCH;++s) y[yb + (size_t)(t0+s)*CC] = f2b(yprev[s]);
    }
    asm volatile("" ::: "memory");
    if (c+2 < RNC){
      int nb = cur+2; if (nb>=3) nb-=3;
      RSTAGE(nb, c+2);
    }
    asm volatile("" ::: "memory");
    const char* bs = lds + cur*RBUF;
    #pragma unroll
    for (int s=0;s<RCH;++s){
      const f32x4* aV = (const f32x4*)(bs + 4096 + s*256 + j0*4);
      float sa = 0.f;
      #pragma unroll
      for (int q=0;q<4;++q){
        f32x4 aq = aV[q];
        #pragma unroll
        for (int e=0;e<4;++e) sa += S[q*4+e]*aq[e];
      }
      sa += __shfl_xor(sa,16); sa += __shfl_xor(sa,32);
      const f32x4* dV = (const f32x4*)(bs + s*256 + j0*4);
      const f32x4* bV = (const f32x4*)(bs + 8192 + s*256 + j0*4);
      const short8* rV = (const short8*)(bs + 12288 + s*128 + j0*2);
      const short8* kV = (const short8*)(bs + 14336 + s*128 + j0*2);
      float vi = b2f(*(const u16*)(bs + 16384 + s*128 + i*2));
      short8 r0 = rV[0], r1 = rV[1];
      short8 k0 = kV[0], k1 = kV[1];
      float yv = 0.f;
      #pragma unroll
      for (int q=0;q<4;++q){
        f32x4 dq = dV[q], bq = bV[q];
        #pragma unroll
        for (int e=0;e<4;++e){
          const int idx = q*4+e;
          float kk = b2fs(idx<8 ? k0[idx] : k1[idx-8]);
          float rr = b2fs(idx<8 ? r0[idx] : r1[idx-8]);
          float Sq = S[idx]*dq[e] + sa*bq[e] + vi*kk;
          S[idx] = Sq;
          yv += Sq*rr;
        }
      }
      yv += __shfl_xor(yv,16); yv += __shfl_xor(yv,32);
      ycur[s] = yv;
    }
    #pragma unroll
    for (int s=0;s<RCH;++s) yprev[s] = ycur[s];
    cur = (cur+1==3)?0:cur+1;
  }
#undef RSTAGE
  // final chunk's y
  {
    int t0 = (RNC-1)*RCH;
    #pragma unroll
    for (int s=0;s<RCH;++s) y[yb + (size_t)(t0+s)*CC] = f2b(yprev[s]);
  }
}

// ---------------- groupnorm + rk*v + gate -> z bf16
__global__ __launch_bounds__(256) void k_gn(
  const u16* __restrict__ y, const u16* __restrict__ rb, const u16* __restrict__ kb,
  const u16* __restrict__ vb, const float* __restrict__ r_k,
  const float* __restrict__ gnw, const float* __restrict__ gnb,
  const u16* __restrict__ gg, u16* __restrict__ z)
{
  int idx = blockIdx.x*4 + (threadIdx.x>>6);
  int l = threadIdx.x&63;
  int m = idx>>5, h = idx&31;
  int c = h*64 + l;
  size_t mo = (size_t)m*CC + c;
  float yv = b2f(y[mo]);
  float s = yv;
  #pragma unroll
  for (int o=32;o;o>>=1) s += __shfl_xor(s,o);
  float mean = s*(1.f/64.f);
  float dv = yv - mean;
  float vs = dv*dv;
  #pragma unroll
  for (int o=32;o;o>>=1) vs += __shfl_xor(vs,o);
  float gn = dv*rsqrtf(vs*(1.f/64.f) + 6.4e-4f)*gnw[c] + gnb[c];
  size_t ro = ((size_t)((m/TT)*HH + h)*TT + (m%TT))*64 + l;
  float rv=b2f(rb[ro]), kv=b2f(kb[ro]), vv=b2f(vb[ro]);
  float p = rv*kv*r_k[c];
  #pragma unroll
  for (int o=32;o;o>>=1) p += __shfl_xor(p,o);
  z[mo] = f2b((gn + p*vv)*b2f(gg[mo]));
}

extern "C" void kernel_launch(void* const* d_in, const int* in_sizes, int n_in,
                              void* d_out, int out_size, void* d_ws, size_t ws_size,
                              hipStream_t stream)
{
  (void)out_size;
  const float* x      = (const float*)d_in[0];
  const float* v_first= (const float*)d_in[1];
  const float* ln1_w  = (const float*)d_in[2];
  const float* ln1_b  = (const float*)d_in[3];
  const float* ln2_w  = (const float*)d_in[4];
  const float* ln2_b  = (const float*)d_in[5];
  const float* x_r    = (const float*)d_in[6];
  const float* x_w    = (const float*)d_in[7];
  const float* x_k    = (const float*)d_in[8];
  const float* x_v    = (const float*)d_in[9];
  const float* x_a    = (const float*)d_in[10];
  const float* x_g    = (const float*)d_in[11];
  const float* w0     = (const float*)d_in[12];
  const float* w1     = (const float*)d_in[13];
  const float* w2     = (const float*)d_in[14];
  const float* a0     = (const float*)d_in[15];
  const float* a1     = (const float*)d_in[16];
  const float* a2     = (const float*)d_in[17];
  const float* v0     = (const float*)d_in[18];
  const float* v1     = (const float*)d_in[19];
  const float* v2     = (const float*)d_in[20];
  const float* g1     = (const float*)d_in[21];
  const float* g2     = (const float*)d_in[22];
  const float* k_k    = (const float*)d_in[23];
  const float* k_a    = (const float*)d_in[24];
  const float* r_k    = (const float*)d_in[25];
  const float* W_r    = (const float*)d_in[26];
  const float* W_k    = (const float*)d_in[27];
  const float* W_v    = (const float*)d_in[28];
  const float* W_o    = (const float*)d_in[29];
  const float* gn_w   = (const float*)d_in[30];
  const float* gn_b   = (const float*)d_in[31];
  const float* ffn_x_k= (const float*)d_in[32];
  const float* W_key  = (const float*)d_in[33];
  const float* W_val  = (const float*)d_in[34];

  const size_t ME = (size_t)MM*CC;
  float* outF = (float*)d_out;

  bool ok = (n_in==35)
    && in_sizes[0]==6291456 && in_sizes[1]==6291456 && in_sizes[2]==2048
    && in_sizes[12]==2048 && in_sizes[13]==196608 && in_sizes[14]==196608
    && in_sizes[16]==196608 && in_sizes[19]==131072 && in_sizes[21]==524288
    && in_sizes[25]==2048 && in_sizes[26]==4194304 && in_sizes[33]==16777216
    && in_sizes[34]==16777216;
  if (!ok){
    k_fillf<<<2048, 256, 0, stream>>>(outF, 1099511627776.f, (int)ME);
    return;
  }

  constexpr size_t WS_NEED = 125829120 + 12582912;
  if (ws_size < WS_NEED){
    k_fillf<<<2048, 256, 0, stream>>>(outF, (float)(1u<<21) * (float)(ws_size>>20), (int)ME);
    return;
  }
  char* ws = (char*)d_ws;
  float* decay = (float*)(ws + 0);
  float* x1    = (float*)(ws + 0);
  u16* xn   = (u16*)(ws + 25165824);
  u16* WT   = (u16*)(ws + 25165824);
  float* bf32 = (float*)(ws + 25165824);
  u16* xw  = (u16*)(ws + 37748736);
  u16* xr  = (u16*)(ws + 37748736);
  u16* xn2 = (u16*)(ws + 37748736);
  float* af32 = (float*)(ws + 50331648);
  u16* xa  = (u16*)(ws + 50331648);
  u16* xk  = (u16*)(ws + 50331648);
  u16* xv  = (u16*)(ws + 62914560);
  u16* kf  = (u16*)(ws + 62914560);
  u16* xg  = (u16*)(ws + 75497472);
  u16* rsc = (u16*)(ws + 75497472);
  char* Fs = ws + 88080384;
  u16* B1T = (u16*)(Fs);
  u16* w2T = (u16*)(Fs + 2621440);
  u16* a2T = (u16*)(Fs + 3014656);
  u16* v2T = (u16*)(Fs + 3407872);
  u16* g2T = (u16*)(Fs + 3670016);
  u16* H1b = (u16*)(Fs + 4718592);
  u16* ksc = (u16*)(ws + 88080384);
  u16* asc = (u16*)(ws + 100663296);
  u16* ybuf= (u16*)(ws + 100663296);
  u16* gsc = (u16*)(ws + 113246208);
  u16* zbuf= (u16*)(ws + 113246208);
  u16* xcm = (u16*)(ws + 113246208);
  u16* WbigT = (u16*)(ws + 25165824);
  u16* outG = (u16*)(ws + 125829120);
  u16* vsc   = (u16*)d_out;
  u16* WrkvT = ((u16*)d_out) + ME;

  auto GEMM = [&](const u16* a0_, const u16* a1_, const u16* a2_,
                  int amode, int lda_, const u16* bt, int ldb_,
                  void* c0_, void* c1_, void* c2_, int ldc_,
                  int N_, int K_, int em, const float* aux_){
    k_gemm<<<dim3(N_/128, MM/128), 256, 0, stream>>>(a0_,a1_,a2_,amode,lda_,bt,ldb_,c0_,c1_,c2_,ldc_,K_,em,aux_);
  };
  dim3 tb(32,8);

  k_lnb<<<MM, 256, 0, stream>>>(x, ln1_w, ln1_b, xn);
  k_mixA<<<MM, 256, 0, stream>>>(xn, x_w, x_a, x_v, x_g, xw, xa, xv, xg);
  hipMemsetAsync(B1T, 0, 2621440, stream);
  k_tpose<<<dim3(3,64), tb, 0, stream>>>(w1, 2048,  96, B1T + 0*2048,   2048);
  k_tpose<<<dim3(3,64), tb, 0, stream>>>(a1, 2048,  96, B1T + 128*2048, 2048);
  k_tpose<<<dim3(2,64), tb, 0, stream>>>(v1, 2048,  64, B1T + 256*2048, 2048);
  k_tpose<<<dim3(8,64), tb, 0, stream>>>(g1, 2048, 256, B1T + 384*2048, 2048);
  k_tpose<<<dim3(64,3), tb, 0, stream>>>(w2,   96, 2048, w2T,  96);
  k_tpose<<<dim3(64,3), tb, 0, stream>>>(a2,   96, 2048, a2T,  96);
  k_tpose<<<dim3(64,2), tb, 0, stream>>>(v2,   64, 2048, v2T,  64);
  k_tpose<<<dim3(64,8), tb, 0, stream>>>(g2,  256, 2048, g2T, 256);
  GEMM(xw, xa, xv, 1, 2048, B1T, 2048, H1b, nullptr, nullptr, 640, 384, 2048, 7, nullptr);
  GEMM(xg, xg, xg, 0, 2048, B1T + 384*2048, 2048, H1b, nullptr, nullptr, 640, 256, 2048, 11, nullptr);
  GEMM(H1b + 0,   H1b, H1b, 0, 640, w2T,  96, decay, nullptr, nullptr, 2048, 2048,  96, 1, w0);
  GEMM(H1b + 128, H1b, H1b, 0, 640, a2T,  96, asc,   nullptr, nullptr, 2048, 2048,  96, 9, a0);
  GEMM(H1b + 256, H1b, H1b, 0, 640, v2T,  64, gsc,   nullptr, nullptr, 2048, 2048,  64, 9, v0);
  GEMM(H1b + 384, H1b, H1b, 0, 640, g2T, 256, outG,  nullptr, nullptr, 2048, 2048, 256, 6, nullptr);
  k_mixB<<<MM, 256, 0, stream>>>(xn, x_r, x_k, xr, xk);
  k_tpose<<<dim3(64,64), tb, 0, stream>>>(W_r, 2048, 2048, WrkvT,               2048);
  k_tpose<<<dim3(64,64), tb, 0, stream>>>(W_k, 2048, 2048, WrkvT + 2048*2048,   2048);
  k_tpose<<<dim3(64,64), tb, 0, stream>>>(W_v, 2048, 2048, WrkvT + 2*2048*2048, 2048);
  GEMM(xr, xk, xv, 2, 2048, WrkvT, 2048, rsc, ksc, vsc, 2048, 6144, 2048, 10, nullptr);
  k_make_rec3<<<MM*HH/4, 256, 0, stream>>>(ksc, vsc, asc, gsc, af32, bf32, v_first, k_k, k_a);
  k_rwkv<<<128, 256, 0, stream>>>(decay, af32, bf32, rsc, ksc, vsc, ybuf);
  k_gn<<<MM*HH/4, 256, 0, stream>>>(ybuf, rsc, ksc, vsc, r_k, gn_w, gn_b, outG, zbuf);
  k_tpose<<<dim3(64,64), tb, 0, stream>>>(W_o, 2048, 2048, WT, 2048);
  GEMM(zbuf, zbuf, zbuf, 0, 2048, WT, 2048, x1, nullptr, nullptr, 2048, 2048, 2048, 3, x);
  k_lnb<<<MM, 256, 0, stream>>>(x1, ln2_w, ln2_b, xn2);
  k_mix1<<<MM, 256, 0, stream>>>(xn2, ffn_x_k, xcm);
  k_tpose<<<dim3(256,64), tb, 0, stream>>>(W_key, 2048, 8192, WbigT, 2048);
  GEMM(xcm, xcm, xcm, 0, 2048, WbigT, 2048, kf, nullptr, nullptr, 8192, 8192, 2048, 4, nullptr);
  k_tpose<<<dim3(64,256), tb, 0, stream>>>(W_val, 8192, 2048, WbigT, 8192);
  GEMM(kf, kf, kf, 0, 8192, WbigT, 8192, outF, nullptr, nullptr, 2048, 2048, 8192, 3, x1);
  hipMemcpyAsync(outF + ME, v_first, ME*sizeof(float), hipMemcpyDeviceToDevice, stream);
}

// Round 15
// 1469.854 us; speedup vs baseline: 3.1655x; 1.0553x over previous
//
#include <hip/hip_runtime.h>
#include <stdint.h>

typedef unsigned short u16;
typedef __attribute__((ext_vector_type(8))) short short8;
typedef __attribute__((ext_vector_type(4))) float f32x4;

#define DEVI __device__ __forceinline__

static constexpr int TT = 768;
static constexpr int CC = 2048;
static constexpr int MM = 3072;
static constexpr int HH = 32;

DEVI float b2f(u16 u){ union{float f; unsigned int i;} x; x.i = ((unsigned int)u)<<16; return x.f; }
DEVI float b2fs(short s){ return b2f((u16)s); }
DEVI u16 f2b(float f){
  unsigned int u = __builtin_bit_cast(unsigned int, f);
  unsigned int r = (u + 0x7fffu + ((u>>16)&1u)) >> 16;
  return (u16)r;
}

DEVI void gload16(const void* g, void* s){
  __builtin_amdgcn_global_load_lds((const __attribute__((address_space(1))) void*)g,
                                   (__attribute__((address_space(3))) void*)s, 16, 0, 0);
}

__global__ __launch_bounds__(256) void k_fillf(float* __restrict__ out, float v, int n){
  for (int i = blockIdx.x*256 + threadIdx.x; i < n; i += gridDim.x*256) out[i] = v;
}

__global__ void k_tpose(const float* __restrict__ src, int R, int Cn, u16* __restrict__ dst, int ldd){
  __shared__ float tile[32][33];
  int c0 = blockIdx.x*32, r0 = blockIdx.y*32;
  #pragma unroll
  for (int i=0;i<4;++i){
    int r = r0 + threadIdx.y + i*8, c = c0 + threadIdx.x;
    tile[threadIdx.y + i*8][threadIdx.x] = (r<R && c<Cn) ? src[(size_t)r*Cn + c] : 0.f;
  }
  __syncthreads();
  #pragma unroll
  for (int i=0;i<4;++i){
    int c = c0 + threadIdx.y + i*8, r = r0 + threadIdx.x;
    if (c<Cn && r<R) dst[(size_t)c*ldd + r] = f2b(tile[threadIdx.x][threadIdx.y + i*8]);
  }
}

__global__ __launch_bounds__(256) void k_lnb(const float* __restrict__ in, const float* __restrict__ w,
                                             const float* __restrict__ bias, u16* __restrict__ out){
  __shared__ float red[8];
  int m = blockIdx.x;
  const float* x = in + (size_t)m*CC;
  float v[8]; float s=0.f, ss=0.f;
  #pragma unroll
  for (int i=0;i<8;++i){ v[i] = x[threadIdx.x + i*256]; s += v[i]; ss += v[i]*v[i]; }
  #pragma unroll
  for (int o=32;o;o>>=1){ s += __shfl_xor(s,o); ss += __shfl_xor(ss,o); }
  int wid = threadIdx.x>>6;
  if ((threadIdx.x&63)==0){ red[wid]=s; red[4+wid]=ss; }
  __syncthreads();
  s  = red[0]+red[1]+red[2]+red[3];
  ss = red[4]+red[5]+red[6]+red[7];
  float mean = s*(1.f/2048.f);
  float var  = ss*(1.f/2048.f) - mean*mean;
  float rstd = rsqrtf(fmaxf(var,0.f) + 1e-5f);
  #pragma unroll
  for (int i=0;i<8;++i){
    int c = threadIdx.x + i*256;
    out[(size_t)m*CC + c] = f2b((v[i]-mean)*rstd*w[c] + bias[c]);
  }
}

__global__ __launch_bounds__(256) void k_mixA(const u16* __restrict__ xn,
  const float* __restrict__ cw, const float* __restrict__ ca, const float* __restrict__ cv,
  const float* __restrict__ cg,
  u16* __restrict__ ow, u16* __restrict__ oa, u16* __restrict__ ov, u16* __restrict__ og)
{
  int m = blockIdx.x; int t = m % TT;
  const u16* cur = xn + (size_t)m*CC;
  const u16* prv = cur - CC;
  bool has = (t>0);
  #pragma unroll
  for (int i=0;i<8;++i){
    int c = threadIdx.x + i*256;
    float xc = b2f(cur[c]);
    float xx = (has ? b2f(prv[c]) : 0.f) - xc;
    size_t o = (size_t)m*CC + c;
    ow[o]=f2b(xc + xx*cw[c]); oa[o]=f2b(xc + xx*ca[c]);
    ov[o]=f2b(xc + xx*cv[c]); og[o]=f2b(xc + xx*cg[c]);
  }
}

__global__ __launch_bounds__(256) void k_mixB(const u16* __restrict__ xn,
  const float* __restrict__ cr, const float* __restrict__ ck,
  u16* __restrict__ orr, u16* __restrict__ ok)
{
  int m = blockIdx.x; int t = m % TT;
  const u16* cur = xn + (size_t)m*CC;
  const u16* prv = cur - CC;
  bool has = (t>0);
  #pragma unroll
  for (int i=0;i<8;++i){
    int c = threadIdx.x + i*256;
    float xc = b2f(cur[c]);
    float xx = (has ? b2f(prv[c]) : 0.f) - xc;
    size_t o = (size_t)m*CC + c;
    orr[o]=f2b(xc + xx*cr[c]); ok[o]=f2b(xc + xx*ck[c]);
  }
}

__global__ __launch_bounds__(256) void k_mix1(const u16* __restrict__ xn, const float* __restrict__ cf,
                                              u16* __restrict__ out){
  int m = blockIdx.x; int t = m % TT;
  const u16* cur = xn + (size_t)m*CC;
  const u16* prv = cur - CC;
  bool has = (t>0);
  #pragma unroll
  for (int i=0;i<8;++i){
    int c = threadIdx.x + i*256;
    float xc = b2f(cur[c]);
    float xx = (has ? b2f(prv[c]) : 0.f) - xc;
    out[(size_t)m*CC + c] = f2b(xc + xx*cf[c]);
  }
}

// ---------------- bf16 MFMA GEMM: 128x128 tile, BK=32, TRI-buffered depth-2 prefetch,
// raw s_barrier + counted vmcnt(4), XCD swizzle.  (unchanged — proven r13/r14)
__global__ __launch_bounds__(256,2) void k_gemm(
    const u16* A0, const u16* A1, const u16* A2,
    int amode, int lda,
    const u16* __restrict__ BT, int ldb,
    void* C0, void* C1, void* C2, int ldc, int K,
    int emode, const float* __restrict__ aux)
{
  const int tid = threadIdx.x;
  const int w = tid>>6, l = tid&63;

  const int NT = gridDim.x;
  const int nwg = NT * gridDim.y;
  int bid = blockIdx.y * NT + blockIdx.x;
  int qq = nwg >> 3, rr = nwg & 7;
  int xcd = bid & 7, pos = bid >> 3;
  int nid = (xcd < rr ? xcd*(qq+1) : rr*(qq+1) + (xcd-rr)*qq) + pos;
  const int ntile = nid % NT;
  const int mtile = nid / NT;

  const u16* A = A0;
  if (amode==1){ A = (ntile==0)?A0:(ntile==1)?A1:A2; }
  else if (amode==2){ int g = ntile>>4; A = (g==0)?A0:(g==1)?A1:A2; }

  __shared__ __align__(16) u16 As[3*4096];
  __shared__ __align__(16) u16 Bs[3*4096];

  const int sr = w*16 + (l>>2);
  const int sk = (l&3)*8;
  const u16* Ag = A  + (size_t)(mtile*128 + sr)*lda + sk;
  const u16* Bg = BT + (size_t)(ntile*128 + sr)*ldb + sk;
  const size_t a64 = (size_t)64*lda, b64 = (size_t)64*ldb;
  const int wo = w*512;

  const int wm = w>>1, wn = w&1;
  const int fr = l&15, fk = (l>>4)*8;
  const int aoff = (wm*64 + fr)*32 + fk;
  const int boff = (wn*64 + fr)*32 + fk;

  f32x4 acc[4][4];
  const f32x4 zz = {0.f,0.f,0.f,0.f};
  #pragma unroll
  for (int mi=0;mi<4;++mi)
    #pragma unroll
    for (int ni=0;ni<4;++ni) acc[mi][ni] = zz;

  const int nt = K >> 5;

#define STAGE(bufi, k0) do{ \
    u16* dA = As + (bufi)*4096 + wo; \
    u16* dB = Bs + (bufi)*4096 + wo; \
    gload16(Ag + (k0),        dA); \
    gload16(Ag + a64 + (k0),  dA + 2048); \
    gload16(Bg + (k0),        dB); \
    gload16(Bg + b64 + (k0),  dB + 2048); \
  }while(0)

  STAGE(0, 0);
  if (nt > 1) STAGE(1, 32);

  int cur = 0;
  for (int t=0; t<nt; ++t){
    if (t == nt-1){ asm volatile("s_waitcnt vmcnt(0)" ::: "memory"); }
    else          { asm volatile("s_waitcnt vmcnt(4)" ::: "memory"); }
    __builtin_amdgcn_s_barrier();
    if (t+2 < nt){
      int nb = cur+2; if (nb>=3) nb-=3;
      STAGE(nb, (t+2)<<5);
    }
    const u16* Ab = As + cur*4096;
    const u16* Bb = Bs + cur*4096;
    short8 af[4], bfr[4];
    #pragma unroll
    for (int mi=0;mi<4;++mi) af[mi]  = *(const short8*)(Ab + aoff + mi*512);
    #pragma unroll
    for (int ni=0;ni<4;++ni) bfr[ni] = *(const short8*)(Bb + boff + ni*512);
    #pragma unroll
    for (int mi=0;mi<4;++mi)
      #pragma unroll
      for (int ni=0;ni<4;++ni)
        acc[mi][ni] = __builtin_amdgcn_mfma_f32_16x16x32_bf16(af[mi], bfr[ni], acc[mi][ni], 0,0,0);
    cur = (cur+1==3)?0:cur+1;
  }
#undef STAGE

  const int rb0 = mtile*128 + wm*64 + (l>>4)*4;
  const int cb0 = ntile*128 + wn*64 + fr;
  #pragma unroll
  for (int mi=0;mi<4;++mi){
    #pragma unroll
    for (int ni=0;ni<4;++ni){
      #pragma unroll
      for (int q2=0;q2<4;++q2){
        int row = rb0 + mi*16 + q2;
        int col = cb0 + ni*16;
        float v = acc[mi][ni][q2];
        if (emode==0){
          ((float*)C0)[(size_t)row*ldc + col] = v;
        } else if (emode==1){
          float valw = aux[col] + v;
          float zneg = -valw;
          float sp = (zneg > 20.f) ? zneg : log1pf(expf(zneg));
          float wlog = -sp - 0.5f;
          float dec = expf(-expf(wlog));
          int b_ = row/TT, t_ = row - b_*TT;
          int h_ = col>>6, n_ = col&63;
          ((float*)C0)[((size_t)(b_*HH + h_)*TT + t_)*64 + n_] = dec;
        } else if (emode==2){
          float s = 1.f/(1.f+expf(-(aux[col]+v)));
          ((u16*)C0)[(size_t)row*ldc + col] = f2b(s);
        } else if (emode==3){
          ((float*)C0)[(size_t)row*ldc + col] = aux[(size_t)row*ldc + col] + v;
        } else if (emode==4){
          float r_ = fmaxf(v, 0.f);
          ((u16*)C0)[(size_t)row*ldc + col] = f2b(r_*r_);
        } else if (emode==5){
          ((u16*)C0)[(size_t)row*ldc + col] = f2b(aux[(size_t)row*ldc + col] + v);
        } else if (emode==6){
          ((u16*)C0)[(size_t)row*ldc + col] = f2b(v);
        } else if (emode==7){
          float r_ = v;
          if (col < 128) r_ = tanhf(v);
          else if (col >= 384) r_ = 1.f/(1.f+expf(-v));
          ((u16*)C0)[(size_t)row*ldc + col] = f2b(r_);
        } else if (emode==8){
          int b_ = row/TT, t_ = row - b_*TT;
          int h_ = col>>6, n_ = col&63;
          ((u16*)C0)[((size_t)(b_*HH + h_)*TT + t_)*64 + n_] = f2b(v);
        } else if (emode==9){
          float s = 1.f/(1.f+expf(-(aux[col]+v)));
          int b_ = row/TT, t_ = row - b_*TT;
          int h_ = col>>6, n_ = col&63;
          ((u16*)C0)[((size_t)(b_*HH + h_)*TT + t_)*64 + n_] = f2b(s);
        } else if (emode==10){
          int g = col>>11, c2 = col&2047;
          int b_ = row/TT, t_ = row - b_*TT;
          int h_ = c2>>6, n_ = c2&63;
          u16* dst = (g==0)?(u16*)C0:(g==1)?(u16*)C1:(u16*)C2;
          dst[((size_t)(b_*HH + h_)*TT + t_)*64 + n_] = f2b(v);
        } else { // 11
          float s = 1.f/(1.f+expf(-v));
          ((u16*)C0)[(size_t)row*ldc + (col+384)] = f2b(s);
        }
      }
    }
  }
}

__global__ __launch_bounds__(256) void k_make_rec3(
  u16* __restrict__ ksc, u16* __restrict__ vsc,
  const u16* __restrict__ asc, const u16* __restrict__ gsc,
  float* __restrict__ af, float* __restrict__ bf,
  const float* __restrict__ v_first, const float* __restrict__ k_k, const float* __restrict__ k_a)
{
  int idx = blockIdx.x*4 + (threadIdx.x>>6);
  int l = threadIdx.x & 63;
  int bh = idx / TT, t = idx - bh*TT;
  int b = bh >> 5, h = bh & 31;
  int c = h*64 + l;
  size_t off = (size_t)idx*64 + l;
  size_t mo = ((size_t)b*TT + t)*CC + c;
  float kq = b2f(ksc[off]);
  float vv = b2f(vsc[off]);
  float aa = b2f(asc[off]);
  float sg = b2f(gsc[off]);
  float vf = v_first[mo];
  float kkr = kq * k_k[c];
  float s2 = kkr*kkr;
  #pragma unroll
  for (int o=32;o;o>>=1) s2 += __shfl_xor(s2,o);
  float kk = kkr / fmaxf(sqrtf(s2), 1e-12f);
  ksc[off] = f2b(kq*(1.f + (aa-1.f)*k_a[c]));
  vsc[off] = f2b(vv + (vf-vv)*sg);
  af[off] = -kk;
  bf[off] = kk*aa;
}

// ---------------- RWKV7 recurrence v3: rows split across 2 blocks per (b,h) -> 256 blocks
// (all CUs active); lane owns 1 row x 8 cols -> 9 LDS insts/wave/step; LDS-staged 16-step
// chunks, tri-buffered, counted vmcnt(6) + raw s_barrier (staging identical to r14).
static constexpr int RCH = 16;
static constexpr int RNC = TT / RCH;           // 48 chunks
static constexpr int RBUF = 18432;             // bytes per chunk buffer

__global__ __launch_bounds__(256,1) void k_rwkv(
    const float* __restrict__ decay, const float* __restrict__ af, const float* __restrict__ bf,
    const u16* __restrict__ rb, const u16* __restrict__ kb, const u16* __restrict__ vb,
    u16* __restrict__ y)
{
  __shared__ __align__(16) char lds[3*RBUF];   // 54 KB
  int blk = blockIdx.x;                        // 256 blocks
  int bh = blk >> 1, half = blk & 1;
  int b = bh>>5, h = bh&31;
  int tid = threadIdx.x, w = tid>>6, l = tid&63;
  const int row = half*32 + w*8 + (l&7);       // state row (v-dim), 32 rows per block
  const int j0 = (l>>3)*8;                     // owned column group (8 cols)
  const size_t base = (size_t)bh * (TT*64);

  const float* dB = decay + base;
  const float* aB = af + base;
  const float* bB = bf + base;
  const u16*  rB = rb + base;
  const u16*  kB = kb + base;
  const u16*  vB = vb + base;

  float S[8];
  #pragma unroll
  for (int q=0;q<8;++q) S[q]=0.f;
  float ycur[RCH], yprev[RCH];
  size_t yb = (size_t)b*TT*CC + h*64 + row;

  // staging thread roles (identical to r14: 6 gload16-insts per wave per chunk)
  const int fe = tid*4;
  const int he = w*256 + l*8;
  const bool hlo = (l < 32);

#define RSTAGE(bufi, c) do{ \
    char* bs = lds + (bufi)*RBUF; \
    size_t cb = (size_t)(c)*1024; \
    gload16(dB + cb + fe, bs + tid*16); \
    gload16(aB + cb + fe, bs + 4096 + tid*16); \
    gload16(bB + cb + fe, bs + 8192 + tid*16); \
    if (hlo){ \
      gload16(rB + cb + he, bs + 12288 + w*512 + l*16); \
      gload16(kB + cb + he, bs + 14336 + w*512 + l*16); \
      gload16(vB + cb + he, bs + 16384 + w*512 + l*16); \
    } \
  }while(0)

  RSTAGE(0, 0);
  RSTAGE(1, 1);

  int cur = 0;
  for (int c=0; c<RNC; ++c){
    if (c == RNC-1){ asm volatile("s_waitcnt vmcnt(0)" ::: "memory"); }
    else           { asm volatile("s_waitcnt vmcnt(6)" ::: "memory"); }
    __builtin_amdgcn_s_barrier();
    if (c > 0){
      int t0 = (c-1)*RCH;
      #pragma unroll
      for (int s=0;s<RCH;++s) if (j0==0) y[yb + (size_t)(t0+s)*CC] = f2b(yprev[s]);
    }
    asm volatile("" ::: "memory");
    if (c+2 < RNC){
      int nb = cur+2; if (nb>=3) nb-=3;
      RSTAGE(nb, c+2);
    }
    asm volatile("" ::: "memory");
    const char* bs = lds + cur*RBUF;
    #pragma unroll
    for (int s=0;s<RCH;++s){
      const f32x4* aV = (const f32x4*)(bs + 4096 + s*256 + j0*4);
      f32x4 a0v = aV[0], a1v = aV[1];
      float sa = ((S[0]*a0v[0] + S[1]*a0v[1]) + (S[2]*a0v[2] + S[3]*a0v[3]))
               + ((S[4]*a1v[0] + S[5]*a1v[1]) + (S[6]*a1v[2] + S[7]*a1v[3]));
      sa += __shfl_xor(sa,8); sa += __shfl_xor(sa,16); sa += __shfl_xor(sa,32);
      const f32x4* dV = (const f32x4*)(bs + s*256 + j0*4);
      const f32x4* bV = (const f32x4*)(bs + 8192 + s*256 + j0*4);
      short8 rv8 = *(const short8*)(bs + 12288 + s*128 + j0*2);
      short8 kv8 = *(const short8*)(bs + 14336 + s*128 + j0*2);
      float vi = b2f(*(const u16*)(bs + 16384 + s*128 + row*2));
      f32x4 d0v = dV[0], d1v = dV[1], b0v = bV[0], b1v = bV[1];
      float y0 = 0.f, y1 = 0.f;
      #pragma unroll
      for (int e=0;e<4;++e){
        float Sq = S[e]*d0v[e] + sa*b0v[e] + vi*b2fs(kv8[e]);
        S[e] = Sq;
        y0 += Sq*b2fs(rv8[e]);
      }
      #pragma unroll
      for (int e=0;e<4;++e){
        float Sq = S[4+e]*d1v[e] + sa*b1v[e] + vi*b2fs(kv8[4+e]);
        S[4+e] = Sq;
        y1 += Sq*b2fs(rv8[4+e]);
      }
      float yv = y0 + y1;
      yv += __shfl_xor(yv,8); yv += __shfl_xor(yv,16); yv += __shfl_xor(yv,32);
      ycur[s] = yv;
    }
    #pragma unroll
    for (int s=0;s<RCH;++s) yprev[s] = ycur[s];
    cur = (cur+1==3)?0:cur+1;
  }
#undef RSTAGE
  {
    int t0 = (RNC-1)*RCH;
    #pragma unroll
    for (int s=0;s<RCH;++s) if (j0==0) y[yb + (size_t)(t0+s)*CC] = f2b(yprev[s]);
  }
}

// ---------------- groupnorm + rk*v + gate -> z bf16
__global__ __launch_bounds__(256) void k_gn(
  const u16* __restrict__ y, const u16* __restrict__ rb, const u16* __restrict__ kb,
  const u16* __restrict__ vb, const float* __restrict__ r_k,
  const float* __restrict__ gnw, const float* __restrict__ gnb,
  const u16* __restrict__ gg, u16* __restrict__ z)
{
  int idx = blockIdx.x*4 + (threadIdx.x>>6);
  int l = threadIdx.x&63;
  int m = idx>>5, h = idx&31;
  int c = h*64 + l;
  size_t mo = (size_t)m*CC + c;
  float yv = b2f(y[mo]);
  float s = yv;
  #pragma unroll
  for (int o=32;o;o>>=1) s += __shfl_xor(s,o);
  float mean = s*(1.f/64.f);
  float dv = yv - mean;
  float vs = dv*dv;
  #pragma unroll
  for (int o=32;o;o>>=1) vs += __shfl_xor(vs,o);
  float gn = dv*rsqrtf(vs*(1.f/64.f) + 6.4e-4f)*gnw[c] + gnb[c];
  size_t ro = ((size_t)((m/TT)*HH + h)*TT + (m%TT))*64 + l;
  float rv=b2f(rb[ro]), kv=b2f(kb[ro]), vv=b2f(vb[ro]);
  float p = rv*kv*r_k[c];
  #pragma unroll
  for (int o=32;o;o>>=1) p += __shfl_xor(p,o);
  z[mo] = f2b((gn + p*vv)*b2f(gg[mo]));
}

extern "C" void kernel_launch(void* const* d_in, const int* in_sizes, int n_in,
                              void* d_out, int out_size, void* d_ws, size_t ws_size,
                              hipStream_t stream)
{
  (void)out_size;
  const float* x      = (const float*)d_in[0];
  const float* v_first= (const float*)d_in[1];
  const float* ln1_w  = (const float*)d_in[2];
  const float* ln1_b  = (const float*)d_in[3];
  const float* ln2_w  = (const float*)d_in[4];
  const float* ln2_b  = (const float*)d_in[5];
  const float* x_r    = (const float*)d_in[6];
  const float* x_w    = (const float*)d_in[7];
  const float* x_k    = (const float*)d_in[8];
  const float* x_v    = (const float*)d_in[9];
  const float* x_a    = (const float*)d_in[10];
  const float* x_g    = (const float*)d_in[11];
  const float* w0     = (const float*)d_in[12];
  const float* w1     = (const float*)d_in[13];
  const float* w2     = (const float*)d_in[14];
  const float* a0     = (const float*)d_in[15];
  const float* a1     = (const float*)d_in[16];
  const float* a2     = (const float*)d_in[17];
  const float* v0     = (const float*)d_in[18];
  const float* v1     = (const float*)d_in[19];
  const float* v2     = (const float*)d_in[20];
  const float* g1     = (const float*)d_in[21];
  const float* g2     = (const float*)d_in[22];
  const float* k_k    = (const float*)d_in[23];
  const float* k_a    = (const float*)d_in[24];
  const float* r_k    = (const float*)d_in[25];
  const float* W_r    = (const float*)d_in[26];
  const float* W_k    = (const float*)d_in[27];
  const float* W_v    = (const float*)d_in[28];
  const float* W_o    = (const float*)d_in[29];
  const float* gn_w   = (const float*)d_in[30];
  const float* gn_b   = (const float*)d_in[31];
  const float* ffn_x_k= (const float*)d_in[32];
  const float* W_key  = (const float*)d_in[33];
  const float* W_val  = (const float*)d_in[34];

  const size_t ME = (size_t)MM*CC;
  float* outF = (float*)d_out;

  bool ok = (n_in==35)
    && in_sizes[0]==6291456 && in_sizes[1]==6291456 && in_sizes[2]==2048
    && in_sizes[12]==2048 && in_sizes[13]==196608 && in_sizes[14]==196608
    && in_sizes[16]==196608 && in_sizes[19]==131072 && in_sizes[21]==524288
    && in_sizes[25]==2048 && in_sizes[26]==4194304 && in_sizes[33]==16777216
    && in_sizes[34]==16777216;
  if (!ok){
    k_fillf<<<2048, 256, 0, stream>>>(outF, 1099511627776.f, (int)ME);
    return;
  }

  constexpr size_t WS_NEED = 125829120 + 12582912;
  if (ws_size < WS_NEED){
    k_fillf<<<2048, 256, 0, stream>>>(outF, (float)(1u<<21) * (float)(ws_size>>20), (int)ME);
    return;
  }
  char* ws = (char*)d_ws;
  float* decay = (float*)(ws + 0);
  float* x1    = (float*)(ws + 0);
  u16* xn   = (u16*)(ws + 25165824);
  u16* WT   = (u16*)(ws + 25165824);
  float* bf32 = (float*)(ws + 25165824);
  u16* xw  = (u16*)(ws + 37748736);
  u16* xr  = (u16*)(ws + 37748736);
  u16* xn2 = (u16*)(ws + 37748736);
  float* af32 = (float*)(ws + 50331648);
  u16* xa  = (u16*)(ws + 50331648);
  u16* xk  = (u16*)(ws + 50331648);
  u16* xv  = (u16*)(ws + 62914560);
  u16* kf  = (u16*)(ws + 62914560);
  u16* xg  = (u16*)(ws + 75497472);
  u16* rsc = (u16*)(ws + 75497472);
  char* Fs = ws + 88080384;
  u16* B1T = (u16*)(Fs);
  u16* w2T = (u16*)(Fs + 2621440);
  u16* a2T = (u16*)(Fs + 3014656);
  u16* v2T = (u16*)(Fs + 3407872);
  u16* g2T = (u16*)(Fs + 3670016);
  u16* H1b = (u16*)(Fs + 4718592);
  u16* ksc = (u16*)(ws + 88080384);
  u16* asc = (u16*)(ws + 100663296);
  u16* ybuf= (u16*)(ws + 100663296);
  u16* gsc = (u16*)(ws + 113246208);
  u16* zbuf= (u16*)(ws + 113246208);
  u16* xcm = (u16*)(ws + 113246208);
  u16* WbigT = (u16*)(ws + 25165824);
  u16* outG = (u16*)(ws + 125829120);
  u16* vsc   = (u16*)d_out;
  u16* WrkvT = ((u16*)d_out) + ME;

  auto GEMM = [&](const u16* a0_, const u16* a1_, const u16* a2_,
                  int amode, int lda_, const u16* bt, int ldb_,
                  void* c0_, void* c1_, void* c2_, int ldc_,
                  int N_, int K_, int em, const float* aux_){
    k_gemm<<<dim3(N_/128, MM/128), 256, 0, stream>>>(a0_,a1_,a2_,amode,lda_,bt,ldb_,c0_,c1_,c2_,ldc_,K_,em,aux_);
  };
  dim3 tb(32,8);

  k_lnb<<<MM, 256, 0, stream>>>(x, ln1_w, ln1_b, xn);
  k_mixA<<<MM, 256, 0, stream>>>(xn, x_w, x_a, x_v, x_g, xw, xa, xv, xg);
  hipMemsetAsync(B1T, 0, 2621440, stream);
  k_tpose<<<dim3(3,64), tb, 0, stream>>>(w1, 2048,  96, B1T + 0*2048,   2048);
  k_tpose<<<dim3(3,64), tb, 0, stream>>>(a1, 2048,  96, B1T + 128*2048, 2048);
  k_tpose<<<dim3(2,64), tb, 0, stream>>>(v1, 2048,  64, B1T + 256*2048, 2048);
  k_tpose<<<dim3(8,64), tb, 0, stream>>>(g1, 2048, 256, B1T + 384*2048, 2048);
  k_tpose<<<dim3(64,3), tb, 0, stream>>>(w2,   96, 2048, w2T,  96);
  k_tpose<<<dim3(64,3), tb, 0, stream>>>(a2,   96, 2048, a2T,  96);
  k_tpose<<<dim3(64,2), tb, 0, stream>>>(v2,   64, 2048, v2T,  64);
  k_tpose<<<dim3(64,8), tb, 0, stream>>>(g2,  256, 2048, g2T, 256);
  GEMM(xw, xa, xv, 1, 2048, B1T, 2048, H1b, nullptr, nullptr, 640, 384, 2048, 7, nullptr);
  GEMM(xg, xg, xg, 0, 2048, B1T + 384*2048, 2048, H1b, nullptr, nullptr, 640, 256, 2048, 11, nullptr);
  GEMM(H1b + 0,   H1b, H1b, 0, 640, w2T,  96, decay, nullptr, nullptr, 2048, 2048,  96, 1, w0);
  GEMM(H1b + 128, H1b, H1b, 0, 640, a2T,  96, asc,   nullptr, nullptr, 2048, 2048,  96, 9, a0);
  GEMM(H1b + 256, H1b, H1b, 0, 640, v2T,  64, gsc,   nullptr, nullptr, 2048, 2048,  64, 9, v0);
  GEMM(H1b + 384, H1b, H1b, 0, 640, g2T, 256, outG,  nullptr, nullptr, 2048, 2048, 256, 6, nullptr);
  k_mixB<<<MM, 256, 0, stream>>>(xn, x_r, x_k, xr, xk);
  k_tpose<<<dim3(64,64), tb, 0, stream>>>(W_r, 2048, 2048, WrkvT,               2048);
  k_tpose<<<dim3(64,64), tb, 0, stream>>>(W_k, 2048, 2048, WrkvT + 2048*2048,   2048);
  k_tpose<<<dim3(64,64), tb, 0, stream>>>(W_v, 2048, 2048, WrkvT + 2*2048*2048, 2048);
  GEMM(xr, xk, xv, 2, 2048, WrkvT, 2048, rsc, ksc, vsc, 2048, 6144, 2048, 10, nullptr);
  k_make_rec3<<<MM*HH/4, 256, 0, stream>>>(ksc, vsc, asc, gsc, af32, bf32, v_first, k_k, k_a);
  k_rwkv<<<256, 256, 0, stream>>>(decay, af32, bf32, rsc, ksc, vsc, ybuf);
  k_gn<<<MM*HH/4, 256, 0, stream>>>(ybuf, rsc, ksc, vsc, r_k, gn_w, gn_b, outG, zbuf);
  k_tpose<<<dim3(64,64), tb, 0, stream>>>(W_o, 2048, 2048, WT, 2048);
  GEMM(zbuf, zbuf, zbuf, 0, 2048, WT, 2048, x1, nullptr, nullptr, 2048, 2048, 2048, 3, x);
  k_lnb<<<MM, 256, 0, stream>>>(x1, ln2_w, ln2_b, xn2);
  k_mix1<<<MM, 256, 0, stream>>>(xn2, ffn_x_k, xcm);
  k_tpose<<<dim3(256,64), tb, 0, stream>>>(W_key, 2048, 8192, WbigT, 2048);
  GEMM(xcm, xcm, xcm, 0, 2048, WbigT, 2048, kf, nullptr, nullptr, 8192, 8192, 2048, 4, nullptr);
  k_tpose<<<dim3(64,256), tb, 0, stream>>>(W_val, 8192, 2048, WbigT, 8192);
  GEMM(kf, kf, kf, 0, 8192, WbigT, 8192, outF, nullptr, nullptr, 2048, 2048, 8192, 3, x1);
  hipMemcpyAsync(outF + ME, v_first, ME*sizeof(float), hipMemcpyDeviceToDevice, stream);
}

// Round 17
// 1402.666 us; speedup vs baseline: 3.3172x; 1.0479x over previous
//
#include <hip/hip_runtime.h>
#include <stdint.h>

typedef unsigned short u16;
typedef __attribute__((ext_vector_type(8))) short short8;
typedef __attribute__((ext_vector_type(4))) float f32x4;

#define DEVI __device__ __forceinline__

static constexpr int TT = 768;
static constexpr int CC = 2048;
static constexpr int MM = 3072;
static constexpr int HH = 32;

DEVI float b2f(u16 u){ union{float f; unsigned int i;} x; x.i = ((unsigned int)u)<<16; return x.f; }
DEVI float b2fs(short s){ return b2f((u16)s); }
DEVI u16 f2b(float f){
  unsigned int u = __builtin_bit_cast(unsigned int, f);
  unsigned int r = (u + 0x7fffu + ((u>>16)&1u)) >> 16;
  return (u16)r;
}

DEVI void gload16(const void* g, void* s){
  __builtin_amdgcn_global_load_lds((const __attribute__((address_space(1))) void*)g,
                                   (__attribute__((address_space(3))) void*)s, 16, 0, 0);
}

// butterfly all-reduce over 8 consecutive lanes: xor1(DPP) + xor2(DPP) + xor4(swizzle)
DEVI float rdx8(float x){
  int xi = __builtin_bit_cast(int, x);
  x += __builtin_bit_cast(float, __builtin_amdgcn_update_dpp(0, xi, 0xB1, 0xF, 0xF, true));
  xi = __builtin_bit_cast(int, x);
  x += __builtin_bit_cast(float, __builtin_amdgcn_update_dpp(0, xi, 0x4E, 0xF, 0xF, true));
  xi = __builtin_bit_cast(int, x);
  x += __builtin_bit_cast(float, __builtin_amdgcn_ds_swizzle(xi, 0x101F));
  return x;
}

__global__ __launch_bounds__(256) void k_fillf(float* __restrict__ out, float v, int n){
  for (int i = blockIdx.x*256 + threadIdx.x; i < n; i += gridDim.x*256) out[i] = v;
}

__global__ void k_tpose(const float* __restrict__ src, int R, int Cn, u16* __restrict__ dst, int ldd){
  __shared__ float tile[32][33];
  int c0 = blockIdx.x*32, r0 = blockIdx.y*32;
  #pragma unroll
  for (int i=0;i<4;++i){
    int r = r0 + threadIdx.y + i*8, c = c0 + threadIdx.x;
    tile[threadIdx.y + i*8][threadIdx.x] = (r<R && c<Cn) ? src[(size_t)r*Cn + c] : 0.f;
  }
  __syncthreads();
  #pragma unroll
  for (int i=0;i<4;++i){
    int c = c0 + threadIdx.y + i*8, r = r0 + threadIdx.x;
    if (c<Cn && r<R) dst[(size_t)c*ldd + r] = f2b(tile[threadIdx.x][threadIdx.y + i*8]);
  }
}

__global__ __launch_bounds__(256) void k_lnb(const float* __restrict__ in, const float* __restrict__ w,
                                             const float* __restrict__ bias, u16* __restrict__ out){
  __shared__ float red[8];
  int m = blockIdx.x;
  const float* x = in + (size_t)m*CC;
  float v[8]; float s=0.f, ss=0.f;
  #pragma unroll
  for (int i=0;i<8;++i){ v[i] = x[threadIdx.x + i*256]; s += v[i]; ss += v[i]*v[i]; }
  #pragma unroll
  for (int o=32;o;o>>=1){ s += __shfl_xor(s,o); ss += __shfl_xor(ss,o); }
  int wid = threadIdx.x>>6;
  if ((threadIdx.x&63)==0){ red[wid]=s; red[4+wid]=ss; }
  __syncthreads();
  s  = red[0]+red[1]+red[2]+red[3];
  ss = red[4]+red[5]+red[6]+red[7];
  float mean = s*(1.f/2048.f);
  float var  = ss*(1.f/2048.f) - mean*mean;
  float rstd = rsqrtf(fmaxf(var,0.f) + 1e-5f);
  #pragma unroll
  for (int i=0;i<8;++i){
    int c = threadIdx.x + i*256;
    out[(size_t)m*CC + c] = f2b((v[i]-mean)*rstd*w[c] + bias[c]);
  }
}

__global__ __launch_bounds__(256) void k_mixA(const u16* __restrict__ xn,
  const float* __restrict__ cw, const float* __restrict__ ca, const float* __restrict__ cv,
  const float* __restrict__ cg,
  u16* __restrict__ ow, u16* __restrict__ oa, u16* __restrict__ ov, u16* __restrict__ og)
{
  int m = blockIdx.x; int t = m % TT;
  const u16* cur = xn + (size_t)m*CC;
  const u16* prv = cur - CC;
  bool has = (t>0);
  #pragma unroll
  for (int i=0;i<8;++i){
    int c = threadIdx.x + i*256;
    float xc = b2f(cur[c]);
    float xx = (has ? b2f(prv[c]) : 0.f) - xc;
    size_t o = (size_t)m*CC + c;
    ow[o]=f2b(xc + xx*cw[c]); oa[o]=f2b(xc + xx*ca[c]);
    ov[o]=f2b(xc + xx*cv[c]); og[o]=f2b(xc + xx*cg[c]);
  }
}

__global__ __launch_bounds__(256) void k_mixB(const u16* __restrict__ xn,
  const float* __restrict__ cr, const float* __restrict__ ck,
  u16* __restrict__ orr, u16* __restrict__ ok)
{
  int m = blockIdx.x; int t = m % TT;
  const u16* cur = xn + (size_t)m*CC;
  const u16* prv = cur - CC;
  bool has = (t>0);
  #pragma unroll
  for (int i=0;i<8;++i){
    int c = threadIdx.x + i*256;
    float xc = b2f(cur[c]);
    float xx = (has ? b2f(prv[c]) : 0.f) - xc;
    size_t o = (size_t)m*CC + c;
    orr[o]=f2b(xc + xx*cr[c]); ok[o]=f2b(xc + xx*ck[c]);
  }
}

__global__ __launch_bounds__(256) void k_mix1(const u16* __restrict__ xn, const float* __restrict__ cf,
                                              u16* __restrict__ out){
  int m = blockIdx.x; int t = m % TT;
  const u16* cur = xn + (size_t)m*CC;
  const u16* prv = cur - CC;
  bool has = (t>0);
  #pragma unroll
  for (int i=0;i<8;++i){
    int c = threadIdx.x + i*256;
    float xc = b2f(cur[c]);
    float xx = (has ? b2f(prv[c]) : 0.f) - xc;
    out[(size_t)m*CC + c] = f2b(xc + xx*cf[c]);
  }
}

// ---------------- bf16 MFMA GEMM: 128x128 tile, BK=32, TRI-buffered depth-2 prefetch,
// raw s_barrier + counted vmcnt(4), XCD swizzle. launch_bounds(256,3).
__global__ __launch_bounds__(256,3) void k_gemm(
    const u16* A0, const u16* A1, const u16* A2,
    int amode, int lda,
    const u16* __restrict__ BT, int ldb,
    void* C0, void* C1, void* C2, int ldc, int K,
    int emode, const float* __restrict__ aux)
{
  const int tid = threadIdx.x;
  const int w = tid>>6, l = tid&63;

  const int NT = gridDim.x;
  const int nwg = NT * gridDim.y;
  int bid = blockIdx.y * NT + blockIdx.x;
  int qq = nwg >> 3, rr = nwg & 7;
  int xcd = bid & 7, pos = bid >> 3;
  int nid = (xcd < rr ? xcd*(qq+1) : rr*(qq+1) + (xcd-rr)*qq) + pos;
  const int ntile = nid % NT;
  const int mtile = nid / NT;

  const u16* A = A0;
  if (amode==1){ A = (ntile==0)?A0:(ntile==1)?A1:A2; }
  else if (amode==2){ int g = ntile>>4; A = (g==0)?A0:(g==1)?A1:A2; }

  __shared__ __align__(16) u16 As[3*4096];
  __shared__ __align__(16) u16 Bs[3*4096];

  const int sr = w*16 + (l>>2);
  const int sk = (l&3)*8;
  const u16* Ag = A  + (size_t)(mtile*128 + sr)*lda + sk;
  const u16* Bg = BT + (size_t)(ntile*128 + sr)*ldb + sk;
  const size_t a64 = (size_t)64*lda, b64 = (size_t)64*ldb;
  const int wo = w*512;

  const int wm = w>>1, wn = w&1;
  const int fr = l&15, fk = (l>>4)*8;
  const int aoff = (wm*64 + fr)*32 + fk;
  const int boff = (wn*64 + fr)*32 + fk;

  f32x4 acc[4][4];
  const f32x4 zz = {0.f,0.f,0.f,0.f};
  #pragma unroll
  for (int mi=0;mi<4;++mi)
    #pragma unroll
    for (int ni=0;ni<4;++ni) acc[mi][ni] = zz;

  const int nt = K >> 5;

#define STAGE(bufi, k0) do{ \
    u16* dA = As + (bufi)*4096 + wo; \
    u16* dB = Bs + (bufi)*4096 + wo; \
    gload16(Ag + (k0),        dA); \
    gload16(Ag + a64 + (k0),  dA + 2048); \
    gload16(Bg + (k0),        dB); \
    gload16(Bg + b64 + (k0),  dB + 2048); \
  }while(0)

  STAGE(0, 0);
  if (nt > 1) STAGE(1, 32);

  int cur = 0;
  for (int t=0; t<nt; ++t){
    if (t == nt-1){ asm volatile("s_waitcnt vmcnt(0)" ::: "memory"); }
    else          { asm volatile("s_waitcnt vmcnt(4)" ::: "memory"); }
    __builtin_amdgcn_s_barrier();
    if (t+2 < nt){
      int nb = cur+2; if (nb>=3) nb-=3;
      STAGE(nb, (t+2)<<5);
    }
    const u16* Ab = As + cur*4096;
    const u16* Bb = Bs + cur*4096;
    short8 af[4], bfr[4];
    #pragma unroll
    for (int mi=0;mi<4;++mi) af[mi]  = *(const short8*)(Ab + aoff + mi*512);
    #pragma unroll
    for (int ni=0;ni<4;++ni) bfr[ni] = *(const short8*)(Bb + boff + ni*512);
    #pragma unroll
    for (int mi=0;mi<4;++mi)
      #pragma unroll
      for (int ni=0;ni<4;++ni)
        acc[mi][ni] = __builtin_amdgcn_mfma_f32_16x16x32_bf16(af[mi], bfr[ni], acc[mi][ni], 0,0,0);
    cur = (cur+1==3)?0:cur+1;
  }
#undef STAGE

  const int rb0 = mtile*128 + wm*64 + (l>>4)*4;
  const int cb0 = ntile*128 + wn*64 + fr;
  #pragma unroll
  for (int mi=0;mi<4;++mi){
    #pragma unroll
    for (int ni=0;ni<4;++ni){
      #pragma unroll
      for (int q2=0;q2<4;++q2){
        int row = rb0 + mi*16 + q2;
        int col = cb0 + ni*16;
        float v = acc[mi][ni][q2];
        if (emode==0){
          ((float*)C0)[(size_t)row*ldc + col] = v;
        } else if (emode==1){
          float valw = aux[col] + v;
          float zneg = -valw;
          float sp = (zneg > 20.f) ? zneg : log1pf(expf(zneg));
          float wlog = -sp - 0.5f;
          float dec = expf(-expf(wlog));
          int b_ = row/TT, t_ = row - b_*TT;
          int h_ = col>>6, n_ = col&63;
          ((float*)C0)[((size_t)(b_*HH + h_)*TT + t_)*64 + n_] = dec;
        } else if (emode==2){
          float s = 1.f/(1.f+expf(-(aux[col]+v)));
          ((u16*)C0)[(size_t)row*ldc + col] = f2b(s);
        } else if (emode==3){
          ((float*)C0)[(size_t)row*ldc + col] = aux[(size_t)row*ldc + col] + v;
        } else if (emode==4){
          float r_ = fmaxf(v, 0.f);
          ((u16*)C0)[(size_t)row*ldc + col] = f2b(r_*r_);
        } else if (emode==5){
          ((u16*)C0)[(size_t)row*ldc + col] = f2b(aux[(size_t)row*ldc + col] + v);
        } else if (emode==6){
          ((u16*)C0)[(size_t)row*ldc + col] = f2b(v);
        } else if (emode==7){
          float r_ = v;
          if (col < 128) r_ = tanhf(v);
          else if (col >= 384) r_ = 1.f/(1.f+expf(-v));
          ((u16*)C0)[(size_t)row*ldc + col] = f2b(r_);
        } else if (emode==8){
          int b_ = row/TT, t_ = row - b_*TT;
          int h_ = col>>6, n_ = col&63;
          ((u16*)C0)[((size_t)(b_*HH + h_)*TT + t_)*64 + n_] = f2b(v);
        } else if (emode==9){
          float s = 1.f/(1.f+expf(-(aux[col]+v)));
          int b_ = row/TT, t_ = row - b_*TT;
          int h_ = col>>6, n_ = col&63;
          ((u16*)C0)[((size_t)(b_*HH + h_)*TT + t_)*64 + n_] = f2b(s);
        } else if (emode==10){
          int g = col>>11, c2 = col&2047;
          int b_ = row/TT, t_ = row - b_*TT;
          int h_ = c2>>6, n_ = c2&63;
          u16* dst = (g==0)?(u16*)C0:(g==1)?(u16*)C1:(u16*)C2;
          dst[((size_t)(b_*HH + h_)*TT + t_)*64 + n_] = f2b(v);
        } else { // 11
          float s = 1.f/(1.f+expf(-v));
          ((u16*)C0)[(size_t)row*ldc + (col+384)] = f2b(s);
        }
      }
    }
  }
}

// ---------------- rec prep: k,v in place; a,b to f32 buffers (r15 semantics — proven)
__global__ __launch_bounds__(256) void k_make_rec3(
  u16* __restrict__ ksc, u16* __restrict__ vsc,
  const u16* __restrict__ asc, const u16* __restrict__ gsc,
  float* __restrict__ af, float* __restrict__ bf,
  const float* __restrict__ v_first, const float* __restrict__ k_k, const float* __restrict__ k_a)
{
  int idx = blockIdx.x*4 + (threadIdx.x>>6);
  int l = threadIdx.x & 63;
  int bh = idx / TT, t = idx - bh*TT;
  int b = bh >> 5, h = bh & 31;
  int c = h*64 + l;
  size_t off = (size_t)idx*64 + l;
  size_t mo = ((size_t)b*TT + t)*CC + c;
  float kq = b2f(ksc[off]);
  float vv = b2f(vsc[off]);
  float aa = b2f(asc[off]);
  float sg = b2f(gsc[off]);
  float vf = v_first[mo];
  float kkr = kq * k_k[c];
  float s2 = kkr*kkr;
  #pragma unroll
  for (int o=32;o;o>>=1) s2 += __shfl_xor(s2,o);
  float kk = kkr / fmaxf(sqrtf(s2), 1e-12f);
  ksc[off] = f2b(kq*(1.f + (aa-1.f)*k_a[c]));
  vsc[off] = f2b(vv + (vf-vv)*sg);
  af[off] = -kk;
  bf[off] = kk*aa;
}

// ---------------- RWKV7 recurrence v5: 256 blocks (2 per (b,h)); lane = (row l>>3, colgroup l&7);
// f32 a,b (proven precision); reductions via DPP xor1/xor2 + swizzle xor4;
// LDS chunks tri-buffered, counted vmcnt(6) + raw s_barrier.
static constexpr int RCH = 16;
static constexpr int RNC = TT / RCH;           // 48
static constexpr int RBUF = 18432;             // d 4096 | a 4096 | b 4096 | r 2048 | k 2048 | v 2048

__global__ __launch_bounds__(256,1) void k_rwkv(
    const float* __restrict__ decay, const float* __restrict__ af, const float* __restrict__ bf,
    const u16* __restrict__ rb, const u16* __restrict__ kb, const u16* __restrict__ vb,
    u16* __restrict__ y)
{
  __shared__ __align__(16) char lds[3*RBUF];   // 54 KB
  int blk = blockIdx.x;
  int bh = blk >> 1, half = blk & 1;
  int b = bh>>5, h = bh&31;
  int tid = threadIdx.x, w = tid>>6, l = tid&63;
  const int row = half*32 + w*8 + (l>>3);
  const int g = l&7;
  const int j0 = g*8;
  const size_t base = (size_t)bh * (TT*64);

  const float* dB = decay + base;
  const float* aB = af + base;
  const float* bB = bf + base;
  const u16*  rB = rb + base;
  const u16*  kB = kb + base;
  const u16*  vB = vb + base;

  float S[8];
  #pragma unroll
  for (int q=0;q<8;++q) S[q]=0.f;
  float ycur[RCH], yprev[RCH];
  size_t yb = (size_t)b*TT*CC + h*64 + row;

#define RSTAGE(bufi, c) do{ \
    char* bs = lds + (bufi)*RBUF; \
    size_t cf = (size_t)(c)*1024; \
    gload16(dB + cf + tid*4, bs + tid*16); \
    gload16(aB + cf + tid*4, bs + 4096 + tid*16); \
    gload16(bB + cf + tid*4, bs + 8192 + tid*16); \
    if (l < 32){ \
      int eo = w*256 + l*8; int bo = w*512 + l*16; \
      gload16(rB + cf + eo, bs + 12288 + bo); \
      gload16(kB + cf + eo, bs + 14336 + bo); \
      gload16(vB + cf + eo, bs + 16384 + bo); \
    } \
  }while(0)

  RSTAGE(0, 0);
  RSTAGE(1, 1);

  int cur = 0;
  for (int c=0; c<RNC; ++c){
    if (c == RNC-1){ asm volatile("s_waitcnt vmcnt(0)" ::: "memory"); }
    else           { asm volatile("s_waitcnt vmcnt(6)" ::: "memory"); }
    __builtin_amdgcn_s_barrier();
    if (c > 0){
      int t0 = (c-1)*RCH;
      #pragma unroll
      for (int s=0;s<RCH;++s) if (g==0) y[yb + (size_t)(t0+s)*CC] = f2b(yprev[s]);
    }
    asm volatile("" ::: "memory");
    if (c+2 < RNC){
      int nb = cur+2; if (nb>=3) nb-=3;
      RSTAGE(nb, c+2);
    }
    asm volatile("" ::: "memory");
    const char* bs = lds + cur*RBUF;
    #pragma unroll
    for (int s=0;s<RCH;++s){
      const f32x4* aV = (const f32x4*)(bs + 4096 + s*256 + j0*4);
      f32x4 a0v = aV[0], a1v = aV[1];
      float sa = ((S[0]*a0v[0] + S[1]*a0v[1]) + (S[2]*a0v[2] + S[3]*a0v[3]))
               + ((S[4]*a1v[0] + S[5]*a1v[1]) + (S[6]*a1v[2] + S[7]*a1v[3]));
      sa = rdx8(sa);
      const f32x4* dV = (const f32x4*)(bs + s*256 + j0*4);
      const f32x4* bV = (const f32x4*)(bs + 8192 + s*256 + j0*4);
      f32x4 d0v = dV[0], d1v = dV[1], b0v = bV[0], b1v = bV[1];
      short8 r8 = *(const short8*)(bs + 12288 + s*128 + j0*2);
      short8 k8 = *(const short8*)(bs + 14336 + s*128 + j0*2);
      float vi = b2f(*(const u16*)(bs + 16384 + s*128 + row*2));
      float yv = 0.f;
      #pragma unroll
      for (int e=0;e<4;++e){
        float Sq = S[e]*d0v[e] + sa*b0v[e] + vi*b2fs(k8[e]);
        S[e] = Sq;
        yv += Sq*b2fs(r8[e]);
      }
      #pragma unroll
      for (int e=0;e<4;++e){
        float Sq = S[4+e]*d1v[e] + sa*b1v[e] + vi*b2fs(k8[4+e]);
        S[4+e] = Sq;
        yv += Sq*b2fs(r8[4+e]);
      }
      ycur[s] = rdx8(yv);
    }
    #pragma unroll
    for (int s=0;s<RCH;++s) yprev[s] = ycur[s];
    cur = (cur+1==3)?0:cur+1;
  }
#undef RSTAGE
  {
    int t0 = (RNC-1)*RCH;
    #pragma unroll
    for (int s=0;s<RCH;++s) if (g==0) y[yb + (size_t)(t0+s)*CC] = f2b(yprev[s]);
  }
}

// ---------------- groupnorm + rk*v + gate -> z bf16
__global__ __launch_bounds__(256) void k_gn(
  const u16* __restrict__ y, const u16* __restrict__ rb, const u16* __restrict__ kb,
  const u16* __restrict__ vb, const float* __restrict__ r_k,
  const float* __restrict__ gnw, const float* __restrict__ gnb,
  const u16* __restrict__ gg, u16* __restrict__ z)
{
  int idx = blockIdx.x*4 + (threadIdx.x>>6);
  int l = threadIdx.x&63;
  int m = idx>>5, h = idx&31;
  int c = h*64 + l;
  size_t mo = (size_t)m*CC + c;
  float yv = b2f(y[mo]);
  float s = yv;
  #pragma unroll
  for (int o=32;o;o>>=1) s += __shfl_xor(s,o);
  float mean = s*(1.f/64.f);
  float dv = yv - mean;
  float vs = dv*dv;
  #pragma unroll
  for (int o=32;o;o>>=1) vs += __shfl_xor(vs,o);
  float gn = dv*rsqrtf(vs*(1.f/64.f) + 6.4e-4f)*gnw[c] + gnb[c];
  size_t ro = ((size_t)((m/TT)*HH + h)*TT + (m%TT))*64 + l;
  float rv=b2f(rb[ro]), kv=b2f(kb[ro]), vv=b2f(vb[ro]);
  float p = rv*kv*r_k[c];
  #pragma unroll
  for (int o=32;o;o>>=1) p += __shfl_xor(p,o);
  z[mo] = f2b((gn + p*vv)*b2f(gg[mo]));
}

extern "C" void kernel_launch(void* const* d_in, const int* in_sizes, int n_in,
                              void* d_out, int out_size, void* d_ws, size_t ws_size,
                              hipStream_t stream)
{
  (void)out_size;
  const float* x      = (const float*)d_in[0];
  const float* v_first= (const float*)d_in[1];
  const float* ln1_w  = (const float*)d_in[2];
  const float* ln1_b  = (const float*)d_in[3];
  const float* ln2_w  = (const float*)d_in[4];
  const float* ln2_b  = (const float*)d_in[5];
  const float* x_r    = (const float*)d_in[6];
  const float* x_w    = (const float*)d_in[7];
  const float* x_k    = (const float*)d_in[8];
  const float* x_v    = (const float*)d_in[9];
  const float* x_a    = (const float*)d_in[10];
  const float* x_g    = (const float*)d_in[11];
  const float* w0     = (const float*)d_in[12];
  const float* w1     = (const float*)d_in[13];
  const float* w2     = (const float*)d_in[14];
  const float* a0     = (const float*)d_in[15];
  const float* a1     = (const float*)d_in[16];
  const float* a2     = (const float*)d_in[17];
  const float* v0     = (const float*)d_in[18];
  const float* v1     = (const float*)d_in[19];
  const float* v2     = (const float*)d_in[20];
  const float* g1     = (const float*)d_in[21];
  const float* g2     = (const float*)d_in[22];
  const float* k_k    = (const float*)d_in[23];
  const float* k_a    = (const float*)d_in[24];
  const float* r_k    = (const float*)d_in[25];
  const float* W_r    = (const float*)d_in[26];
  const float* W_k    = (const float*)d_in[27];
  const float* W_v    = (const float*)d_in[28];
  const float* W_o    = (const float*)d_in[29];
  const float* gn_w   = (const float*)d_in[30];
  const float* gn_b   = (const float*)d_in[31];
  const float* ffn_x_k= (const float*)d_in[32];
  const float* W_key  = (const float*)d_in[33];
  const float* W_val  = (const float*)d_in[34];

  const size_t ME = (size_t)MM*CC;
  float* outF = (float*)d_out;

  bool ok = (n_in==35)
    && in_sizes[0]==6291456 && in_sizes[1]==6291456 && in_sizes[2]==2048
    && in_sizes[12]==2048 && in_sizes[13]==196608 && in_sizes[14]==196608
    && in_sizes[16]==196608 && in_sizes[19]==131072 && in_sizes[21]==524288
    && in_sizes[25]==2048 && in_sizes[26]==4194304 && in_sizes[33]==16777216
    && in_sizes[34]==16777216;
  if (!ok){
    k_fillf<<<2048, 256, 0, stream>>>(outF, 1099511627776.f, (int)ME);
    return;
  }

  constexpr size_t WS_NEED = 125829120 + 12582912;
  if (ws_size < WS_NEED){
    k_fillf<<<2048, 256, 0, stream>>>(outF, (float)(1u<<21) * (float)(ws_size>>20), (int)ME);
    return;
  }
  char* ws = (char*)d_ws;
  float* decay = (float*)(ws + 0);            // G: decay -> x1
  float* x1    = (float*)(ws + 0);
  u16* xn   = (u16*)(ws + 25165824);          // A: xn -> bf32 head -> WT(Wo) -> WbigT
  u16* WT   = (u16*)(ws + 25165824);
  float* bf32 = (float*)(ws + 25165824);      // [24,48M)
  u16* xw  = (u16*)(ws + 37748736);           // B: xw -> xr -> bf32 tail -> xn2
  u16* xr  = (u16*)(ws + 37748736);
  u16* xn2 = (u16*)(ws + 37748736);
  float* af32 = (float*)(ws + 50331648);      // [48,72M)
  u16* xa  = (u16*)(ws + 50331648);           // C: xa -> xk -> af32 head
  u16* xk  = (u16*)(ws + 50331648);
  u16* xv  = (u16*)(ws + 62914560);           // D: xv -> af32 tail -> kf head
  u16* kf  = (u16*)(ws + 62914560);           // [60,108M)
  u16* xg  = (u16*)(ws + 75497472);           // E: xg -> rsc
  u16* rsc = (u16*)(ws + 75497472);
  char* Fs = ws + 88080384;                   // F: small weights + H1b -> ksc
  u16* B1T = (u16*)(Fs);
  u16* w2T = (u16*)(Fs + 2621440);
  u16* a2T = (u16*)(Fs + 3014656);
  u16* v2T = (u16*)(Fs + 3407872);
  u16* g2T = (u16*)(Fs + 3670016);
  u16* H1b = (u16*)(Fs + 4718592);
  u16* ksc = (u16*)(ws + 88080384);
  u16* asc = (u16*)(ws + 100663296);          // H: asc -> ybuf
  u16* ybuf= (u16*)(ws + 100663296);
  u16* gsc = (u16*)(ws + 113246208);          // I: gsc -> zbuf -> xcm
  u16* zbuf= (u16*)(ws + 113246208);
  u16* xcm = (u16*)(ws + 113246208);
  u16* WbigT = (u16*)(ws + 25165824);         // [24,56M) WkeyT/WvalT
  u16* outG = (u16*)(ws + 125829120);         // J: g bf16
  u16* vsc   = (u16*)d_out;                   // d_out lo scratch
  u16* WrkvT = ((u16*)d_out) + ME;            // d_out [12.6,37.7M) scratch

  auto GEMM = [&](const u16* a0_, const u16* a1_, const u16* a2_,
                  int amode, int lda_, const u16* bt, int ldb_,
                  void* c0_, void* c1_, void* c2_, int ldc_,
                  int N_, int K_, int em, const float* aux_){
    k_gemm<<<dim3(N_/128, MM/128), 256, 0, stream>>>(a0_,a1_,a2_,amode,lda_,bt,ldb_,c0_,c1_,c2_,ldc_,K_,em,aux_);
  };
  dim3 tb(32,8);

  k_lnb<<<MM, 256, 0, stream>>>(x, ln1_w, ln1_b, xn);
  k_mixA<<<MM, 256, 0, stream>>>(xn, x_w, x_a, x_v, x_g, xw, xa, xv, xg);
  hipMemsetAsync(B1T, 0, 2621440, stream);
  k_tpose<<<dim3(3,64), tb, 0, stream>>>(w1, 2048,  96, B1T + 0*2048,   2048);
  k_tpose<<<dim3(3,64), tb, 0, stream>>>(a1, 2048,  96, B1T + 128*2048, 2048);
  k_tpose<<<dim3(2,64), tb, 0, stream>>>(v1, 2048,  64, B1T + 256*2048, 2048);
  k_tpose<<<dim3(8,64), tb, 0, stream>>>(g1, 2048, 256, B1T + 384*2048, 2048);
  k_tpose<<<dim3(64,3), tb, 0, stream>>>(w2,   96, 2048, w2T,  96);
  k_tpose<<<dim3(64,3), tb, 0, stream>>>(a2,   96, 2048, a2T,  96);
  k_tpose<<<dim3(64,2), tb, 0, stream>>>(v2,   64, 2048, v2T,  64);
  k_tpose<<<dim3(64,8), tb, 0, stream>>>(g2,  256, 2048, g2T, 256);
  GEMM(xw, xa, xv, 1, 2048, B1T, 2048, H1b, nullptr, nullptr, 640, 384, 2048, 7, nullptr);
  GEMM(xg, xg, xg, 0, 2048, B1T + 384*2048, 2048, H1b, nullptr, nullptr, 640, 256, 2048, 11, nullptr);
  GEMM(H1b + 0,   H1b, H1b, 0, 640, w2T,  96, decay, nullptr, nullptr, 2048, 2048,  96, 1, w0);
  GEMM(H1b + 128, H1b, H1b, 0, 640, a2T,  96, asc,   nullptr, nullptr, 2048, 2048,  96, 9, a0);
  GEMM(H1b + 256, H1b, H1b, 0, 640, v2T,  64, gsc,   nullptr, nullptr, 2048, 2048,  64, 9, v0);
  GEMM(H1b + 384, H1b, H1b, 0, 640, g2T, 256, outG,  nullptr, nullptr, 2048, 2048, 256, 6, nullptr);
  k_mixB<<<MM, 256, 0, stream>>>(xn, x_r, x_k, xr, xk);
  k_tpose<<<dim3(64,64), tb, 0, stream>>>(W_r, 2048, 2048, WrkvT,               2048);
  k_tpose<<<dim3(64,64), tb, 0, stream>>>(W_k, 2048, 2048, WrkvT + 2048*2048,   2048);
  k_tpose<<<dim3(64,64), tb, 0, stream>>>(W_v, 2048, 2048, WrkvT + 2*2048*2048, 2048);
  GEMM(xr, xk, xv, 2, 2048, WrkvT, 2048, rsc, ksc, vsc, 2048, 6144, 2048, 10, nullptr);
  k_make_rec3<<<MM*HH/4, 256, 0, stream>>>(ksc, vsc, asc, gsc, af32, bf32, v_first, k_k, k_a);
  k_rwkv<<<256, 256, 0, stream>>>(decay, af32, bf32, rsc, ksc, vsc, ybuf);
  k_gn<<<MM*HH/4, 256, 0, stream>>>(ybuf, rsc, ksc, vsc, r_k, gn_w, gn_b, outG, zbuf);
  k_tpose<<<dim3(64,64), tb, 0, stream>>>(W_o, 2048, 2048, WT, 2048);
  GEMM(zbuf, zbuf, zbuf, 0, 2048, WT, 2048, x1, nullptr, nullptr, 2048, 2048, 2048, 3, x);
  k_lnb<<<MM, 256, 0, stream>>>(x1, ln2_w, ln2_b, xn2);
  k_mix1<<<MM, 256, 0, stream>>>(xn2, ffn_x_k, xcm);
  k_tpose<<<dim3(256,64), tb, 0, stream>>>(W_key, 2048, 8192, WbigT, 2048);
  GEMM(xcm, xcm, xcm, 0, 2048, WbigT, 2048, kf, nullptr, nullptr, 8192, 8192, 2048, 4, nullptr);
  k_tpose<<<dim3(64,256), tb, 0, stream>>>(W_val, 8192, 2048, WbigT, 8192);
  GEMM(kf, kf, kf, 0, 8192, WbigT, 8192, outF, nullptr, nullptr, 2048, 2048, 8192, 3, x1);
  hipMemcpyAsync(outF + ME, v_first, ME*sizeof(float), hipMemcpyDeviceToDevice, stream);
}

// Round 18
// 1383.687 us; speedup vs baseline: 3.3627x; 1.0137x over previous
//
#include <hip/hip_runtime.h>
#include <stdint.h>

typedef unsigned short u16;
typedef __attribute__((ext_vector_type(8))) short short8;
typedef __attribute__((ext_vector_type(4))) float f32x4;

#define DEVI __device__ __forceinline__

static constexpr int TT = 768;
static constexpr int CC = 2048;
static constexpr int MM = 3072;
static constexpr int HH = 32;

DEVI float b2f(u16 u){ union{float f; unsigned int i;} x; x.i = ((unsigned int)u)<<16; return x.f; }
DEVI float b2fs(short s){ return b2f((u16)s); }
DEVI u16 f2b(float f){
  unsigned int u = __builtin_bit_cast(unsigned int, f);
  unsigned int r = (u + 0x7fffu + ((u>>16)&1u)) >> 16;
  return (u16)r;
}

DEVI void gload16(const void* g, void* s){
  __builtin_amdgcn_global_load_lds((const __attribute__((address_space(1))) void*)g,
                                   (__attribute__((address_space(3))) void*)s, 16, 0, 0);
}

// all-reduce over 8 consecutive lanes, pure DPP (VALU pipe):
// xor1 (quad_perm 0xB1) + xor2 (quad_perm 0x4E) + cross-quad via row_half_mirror (0x141)
DEVI float rdx8(float x){
  int xi = __builtin_bit_cast(int, x);
  x += __builtin_bit_cast(float, __builtin_amdgcn_update_dpp(0, xi, 0xB1, 0xF, 0xF, true));
  xi = __builtin_bit_cast(int, x);
  x += __builtin_bit_cast(float, __builtin_amdgcn_update_dpp(0, xi, 0x4E, 0xF, 0xF, true));
  xi = __builtin_bit_cast(int, x);
  x += __builtin_bit_cast(float, __builtin_amdgcn_update_dpp(0, xi, 0x141, 0xF, 0xF, true));
  return x;
}

__global__ __launch_bounds__(256) void k_fillf(float* __restrict__ out, float v, int n){
  for (int i = blockIdx.x*256 + threadIdx.x; i < n; i += gridDim.x*256) out[i] = v;
}

__global__ void k_tpose(const float* __restrict__ src, int R, int Cn, u16* __restrict__ dst, int ldd){
  __shared__ float tile[32][33];
  int c0 = blockIdx.x*32, r0 = blockIdx.y*32;
  #pragma unroll
  for (int i=0;i<4;++i){
    int r = r0 + threadIdx.y + i*8, c = c0 + threadIdx.x;
    tile[threadIdx.y + i*8][threadIdx.x] = (r<R && c<Cn) ? src[(size_t)r*Cn + c] : 0.f;
  }
  __syncthreads();
  #pragma unroll
  for (int i=0;i<4;++i){
    int c = c0 + threadIdx.y + i*8, r = r0 + threadIdx.x;
    if (c<Cn && r<R) dst[(size_t)c*ldd + r] = f2b(tile[threadIdx.x][threadIdx.y + i*8]);
  }
}

__global__ __launch_bounds__(256) void k_lnb(const float* __restrict__ in, const float* __restrict__ w,
                                             const float* __restrict__ bias, u16* __restrict__ out){
  __shared__ float red[8];
  int m = blockIdx.x;
  const float* x = in + (size_t)m*CC;
  float v[8]; float s=0.f, ss=0.f;
  #pragma unroll
  for (int i=0;i<8;++i){ v[i] = x[threadIdx.x + i*256]; s += v[i]; ss += v[i]*v[i]; }
  #pragma unroll
  for (int o=32;o;o>>=1){ s += __shfl_xor(s,o); ss += __shfl_xor(ss,o); }
  int wid = threadIdx.x>>6;
  if ((threadIdx.x&63)==0){ red[wid]=s; red[4+wid]=ss; }
  __syncthreads();
  s  = red[0]+red[1]+red[2]+red[3];
  ss = red[4]+red[5]+red[6]+red[7];
  float mean = s*(1.f/2048.f);
  float var  = ss*(1.f/2048.f) - mean*mean;
  float rstd = rsqrtf(fmaxf(var,0.f) + 1e-5f);
  #pragma unroll
  for (int i=0;i<8;++i){
    int c = threadIdx.x + i*256;
    out[(size_t)m*CC + c] = f2b((v[i]-mean)*rstd*w[c] + bias[c]);
  }
}

__global__ __launch_bounds__(256) void k_mixA(const u16* __restrict__ xn,
  const float* __restrict__ cw, const float* __restrict__ ca, const float* __restrict__ cv,
  const float* __restrict__ cg,
  u16* __restrict__ ow, u16* __restrict__ oa, u16* __restrict__ ov, u16* __restrict__ og)
{
  int m = blockIdx.x; int t = m % TT;
  const u16* cur = xn + (size_t)m*CC;
  const u16* prv = cur - CC;
  bool has = (t>0);
  #pragma unroll
  for (int i=0;i<8;++i){
    int c = threadIdx.x + i*256;
    float xc = b2f(cur[c]);
    float xx = (has ? b2f(prv[c]) : 0.f) - xc;
    size_t o = (size_t)m*CC + c;
    ow[o]=f2b(xc + xx*cw[c]); oa[o]=f2b(xc + xx*ca[c]);
    ov[o]=f2b(xc + xx*cv[c]); og[o]=f2b(xc + xx*cg[c]);
  }
}

__global__ __launch_bounds__(256) void k_mixB(const u16* __restrict__ xn,
  const float* __restrict__ cr, const float* __restrict__ ck,
  u16* __restrict__ orr, u16* __restrict__ ok)
{
  int m = blockIdx.x; int t = m % TT;
  const u16* cur = xn + (size_t)m*CC;
  const u16* prv = cur - CC;
  bool has = (t>0);
  #pragma unroll
  for (int i=0;i<8;++i){
    int c = threadIdx.x + i*256;
    float xc = b2f(cur[c]);
    float xx = (has ? b2f(prv[c]) : 0.f) - xc;
    size_t o = (size_t)m*CC + c;
    orr[o]=f2b(xc + xx*cr[c]); ok[o]=f2b(xc + xx*ck[c]);
  }
}

__global__ __launch_bounds__(256) void k_mix1(const u16* __restrict__ xn, const float* __restrict__ cf,
                                              u16* __restrict__ out){
  int m = blockIdx.x; int t = m % TT;
  const u16* cur = xn + (size_t)m*CC;
  const u16* prv = cur - CC;
  bool has = (t>0);
  #pragma unroll
  for (int i=0;i<8;++i){
    int c = threadIdx.x + i*256;
    float xc = b2f(cur[c]);
    float xx = (has ? b2f(prv[c]) : 0.f) - xc;
    out[(size_t)m*CC + c] = f2b(xc + xx*cf[c]);
  }
}

// ---------------- bf16 MFMA GEMM: 128x128 tile, BK=32, TRI-buffered depth-2 prefetch,
// raw s_barrier + counted vmcnt(4), XCD swizzle, LDS 16B-block XOR swizzle (8-way -> 4-way).
// Swizzle (rule 21): linear LDS dest, pre-swizzled SOURCE col-block, swizzled READ block.
__global__ __launch_bounds__(256,3) void k_gemm(
    const u16* A0, const u16* A1, const u16* A2,
    int amode, int lda,
    const u16* __restrict__ BT, int ldb,
    void* C0, void* C1, void* C2, int ldc, int K,
    int emode, const float* __restrict__ aux)
{
  const int tid = threadIdx.x;
  const int w = tid>>6, l = tid&63;

  const int NT = gridDim.x;
  const int nwg = NT * gridDim.y;
  int bid = blockIdx.y * NT + blockIdx.x;
  int qq = nwg >> 3, rr = nwg & 7;
  int xcd = bid & 7, pos = bid >> 3;
  int nid = (xcd < rr ? xcd*(qq+1) : rr*(qq+1) + (xcd-rr)*qq) + pos;
  const int ntile = nid % NT;
  const int mtile = nid / NT;

  const u16* A = A0;
  if (amode==1){ A = (ntile==0)?A0:(ntile==1)?A1:A2; }
  else if (amode==2){ int g = ntile>>4; A = (g==0)?A0:(g==1)?A1:A2; }

  __shared__ __align__(16) u16 As[3*4096];
  __shared__ __align__(16) u16 Bs[3*4096];

  const int sr = w*16 + (l>>2);
  const int sk = (((l&3) ^ ((l>>2)&3)))*8;      // pre-swizzled source col-block
  const u16* Ag = A  + (size_t)(mtile*128 + sr)*lda + sk;
  const u16* Bg = BT + (size_t)(ntile*128 + sr)*ldb + sk;
  const size_t a64 = (size_t)64*lda, b64 = (size_t)64*ldb;
  const int wo = w*512;

  const int wm = w>>1, wn = w&1;
  const int fr = l&15;
  const int fq = ((l>>4) ^ (fr&3))*8;           // swizzled read block
  const int aoff = (wm*64 + fr)*32 + fq;
  const int boff = (wn*64 + fr)*32 + fq;

  f32x4 acc[4][4];
  const f32x4 zz = {0.f,0.f,0.f,0.f};
  #pragma unroll
  for (int mi=0;mi<4;++mi)
    #pragma unroll
    for (int ni=0;ni<4;++ni) acc[mi][ni] = zz;

  const int nt = K >> 5;

#define STAGE(bufi, k0) do{ \
    u16* dA = As + (bufi)*4096 + wo; \
    u16* dB = Bs + (bufi)*4096 + wo; \
    gload16(Ag + (k0),        dA); \
    gload16(Ag + a64 + (k0),  dA + 2048); \
    gload16(Bg + (k0),        dB); \
    gload16(Bg + b64 + (k0),  dB + 2048); \
  }while(0)

  STAGE(0, 0);
  if (nt > 1) STAGE(1, 32);

  int cur = 0;
  for (int t=0; t<nt; ++t){
    if (t == nt-1){ asm volatile("s_waitcnt vmcnt(0)" ::: "memory"); }
    else          { asm volatile("s_waitcnt vmcnt(4)" ::: "memory"); }
    __builtin_amdgcn_s_barrier();
    if (t+2 < nt){
      int nb = cur+2; if (nb>=3) nb-=3;
      STAGE(nb, (t+2)<<5);
    }
    const u16* Ab = As + cur*4096;
    const u16* Bb = Bs + cur*4096;
    short8 af[4], bfr[4];
    #pragma unroll
    for (int mi=0;mi<4;++mi) af[mi]  = *(const short8*)(Ab + aoff + mi*512);
    #pragma unroll
    for (int ni=0;ni<4;++ni) bfr[ni] = *(const short8*)(Bb + boff + ni*512);
    #pragma unroll
    for (int mi=0;mi<4;++mi)
      #pragma unroll
      for (int ni=0;ni<4;++ni)
        acc[mi][ni] = __builtin_amdgcn_mfma_f32_16x16x32_bf16(af[mi], bfr[ni], acc[mi][ni], 0,0,0);
    cur = (cur+1==3)?0:cur+1;
  }
#undef STAGE

  const int rb0 = mtile*128 + wm*64 + (l>>4)*4;
  const int cb0 = ntile*128 + wn*64 + fr;
  #pragma unroll
  for (int mi=0;mi<4;++mi){
    #pragma unroll
    for (int ni=0;ni<4;++ni){
      #pragma unroll
      for (int q2=0;q2<4;++q2){
        int row = rb0 + mi*16 + q2;
        int col = cb0 + ni*16;
        float v = acc[mi][ni][q2];
        if (emode==0){
          ((float*)C0)[(size_t)row*ldc + col] = v;
        } else if (emode==1){
          float valw = aux[col] + v;
          float zneg = -valw;
          float sp = (zneg > 20.f) ? zneg : log1pf(expf(zneg));
          float wlog = -sp - 0.5f;
          float dec = expf(-expf(wlog));
          int b_ = row/TT, t_ = row - b_*TT;
          int h_ = col>>6, n_ = col&63;
          ((float*)C0)[((size_t)(b_*HH + h_)*TT + t_)*64 + n_] = dec;
        } else if (emode==2){
          float s = 1.f/(1.f+expf(-(aux[col]+v)));
          ((u16*)C0)[(size_t)row*ldc + col] = f2b(s);
        } else if (emode==3){
          ((float*)C0)[(size_t)row*ldc + col] = aux[(size_t)row*ldc + col] + v;
        } else if (emode==4){
          float r_ = fmaxf(v, 0.f);
          ((u16*)C0)[(size_t)row*ldc + col] = f2b(r_*r_);
        } else if (emode==5){
          ((u16*)C0)[(size_t)row*ldc + col] = f2b(aux[(size_t)row*ldc + col] + v);
        } else if (emode==6){
          ((u16*)C0)[(size_t)row*ldc + col] = f2b(v);
        } else if (emode==7){
          float r_ = v;
          if (col < 128) r_ = tanhf(v);
          else if (col >= 384) r_ = 1.f/(1.f+expf(-v));
          ((u16*)C0)[(size_t)row*ldc + col] = f2b(r_);
        } else if (emode==8){
          int b_ = row/TT, t_ = row - b_*TT;
          int h_ = col>>6, n_ = col&63;
          ((u16*)C0)[((size_t)(b_*HH + h_)*TT + t_)*64 + n_] = f2b(v);
        } else if (emode==9){
          float s = 1.f/(1.f+expf(-(aux[col]+v)));
          int b_ = row/TT, t_ = row - b_*TT;
          int h_ = col>>6, n_ = col&63;
          ((u16*)C0)[((size_t)(b_*HH + h_)*TT + t_)*64 + n_] = f2b(s);
        } else if (emode==10){
          int g = col>>11, c2 = col&2047;
          int b_ = row/TT, t_ = row - b_*TT;
          int h_ = c2>>6, n_ = c2&63;
          u16* dst = (g==0)?(u16*)C0:(g==1)?(u16*)C1:(u16*)C2;
          dst[((size_t)(b_*HH + h_)*TT + t_)*64 + n_] = f2b(v);
        } else { // 11
          float s = 1.f/(1.f+expf(-v));
          ((u16*)C0)[(size_t)row*ldc + (col+384)] = f2b(s);
        }
      }
    }
  }
}

// ---------------- rec prep: k,v in place; a,b to f32 buffers (proven r15/r17)
__global__ __launch_bounds__(256) void k_make_rec3(
  u16* __restrict__ ksc, u16* __restrict__ vsc,
  const u16* __restrict__ asc, const u16* __restrict__ gsc,
  float* __restrict__ af, float* __restrict__ bf,
  const float* __restrict__ v_first, const float* __restrict__ k_k, const float* __restrict__ k_a)
{
  int idx = blockIdx.x*4 + (threadIdx.x>>6);
  int l = threadIdx.x & 63;
  int bh = idx / TT, t = idx - bh*TT;
  int b = bh >> 5, h = bh & 31;
  int c = h*64 + l;
  size_t off = (size_t)idx*64 + l;
  size_t mo = ((size_t)b*TT + t)*CC + c;
  float kq = b2f(ksc[off]);
  float vv = b2f(vsc[off]);
  float aa = b2f(asc[off]);
  float sg = b2f(gsc[off]);
  float vf = v_first[mo];
  float kkr = kq * k_k[c];
  float s2 = kkr*kkr;
  #pragma unroll
  for (int o=32;o;o>>=1) s2 += __shfl_xor(s2,o);
  float kk = kkr / fmaxf(sqrtf(s2), 1e-12f);
  ksc[off] = f2b(kq*(1.f + (aa-1.f)*k_a[c]));
  vsc[off] = f2b(vv + (vf-vv)*sg);
  af[off] = -kk;
  bf[off] = kk*aa;
}

// ---------------- RWKV7 recurrence: 256 blocks; lane=(row l>>3, colgroup l&7); f32 a,b;
// all-DPP 8-lane reductions; LDS chunks tri-buffered, counted vmcnt(6) + raw s_barrier.
static constexpr int RCH = 16;
static constexpr int RNC = TT / RCH;
static constexpr int RBUF = 18432;

__global__ __launch_bounds__(256,1) void k_rwkv(
    const float* __restrict__ decay, const float* __restrict__ af, const float* __restrict__ bf,
    const u16* __restrict__ rb, const u16* __restrict__ kb, const u16* __restrict__ vb,
    u16* __restrict__ y)
{
  __shared__ __align__(16) char lds[3*RBUF];
  int blk = blockIdx.x;
  int bh = blk >> 1, half = blk & 1;
  int b = bh>>5, h = bh&31;
  int tid = threadIdx.x, w = tid>>6, l = tid&63;
  const int row = half*32 + w*8 + (l>>3);
  const int g = l&7;
  const int j0 = g*8;
  const size_t base = (size_t)bh * (TT*64);

  const float* dB = decay + base;
  const float* aB = af + base;
  const float* bB = bf + base;
  const u16*  rB = rb + base;
  const u16*  kB = kb + base;
  const u16*  vB = vb + base;

  float S[8];
  #pragma unroll
  for (int q=0;q<8;++q) S[q]=0.f;
  float ycur[RCH], yprev[RCH];
  size_t yb = (size_t)b*TT*CC + h*64 + row;

#define RSTAGE(bufi, c) do{ \
    char* bs = lds + (bufi)*RBUF; \
    size_t cf = (size_t)(c)*1024; \
    gload16(dB + cf + tid*4, bs + tid*16); \
    gload16(aB + cf + tid*4, bs + 4096 + tid*16); \
    gload16(bB + cf + tid*4, bs + 8192 + tid*16); \
    if (l < 32){ \
      int eo = w*256 + l*8; int bo = w*512 + l*16; \
      gload16(rB + cf + eo, bs + 12288 + bo); \
      gload16(kB + cf + eo, bs + 14336 + bo); \
      gload16(vB + cf + eo, bs + 16384 + bo); \
    } \
  }while(0)

  RSTAGE(0, 0);
  RSTAGE(1, 1);

  int cur = 0;
  for (int c=0; c<RNC; ++c){
    if (c == RNC-1){ asm volatile("s_waitcnt vmcnt(0)" ::: "memory"); }
    else           { asm volatile("s_waitcnt vmcnt(6)" ::: "memory"); }
    __builtin_amdgcn_s_barrier();
    if (c > 0){
      int t0 = (c-1)*RCH;
      #pragma unroll
      for (int s=0;s<RCH;++s) if (g==0) y[yb + (size_t)(t0+s)*CC] = f2b(yprev[s]);
    }
    asm volatile("" ::: "memory");
    if (c+2 < RNC){
      int nb = cur+2; if (nb>=3) nb-=3;
      RSTAGE(nb, c+2);
    }
    asm volatile("" ::: "memory");
    const char* bs = lds + cur*RBUF;
    #pragma unroll
    for (int s=0;s<RCH;++s){
      const f32x4* aV = (const f32x4*)(bs + 4096 + s*256 + j0*4);
      f32x4 a0v = aV[0], a1v = aV[1];
      float sa = ((S[0]*a0v[0] + S[1]*a0v[1]) + (S[2]*a0v[2] + S[3]*a0v[3]))
               + ((S[4]*a1v[0] + S[5]*a1v[1]) + (S[6]*a1v[2] + S[7]*a1v[3]));
      sa = rdx8(sa);
      const f32x4* dV = (const f32x4*)(bs + s*256 + j0*4);
      const f32x4* bV = (const f32x4*)(bs + 8192 + s*256 + j0*4);
      f32x4 d0v = dV[0], d1v = dV[1], b0v = bV[0], b1v = bV[1];
      short8 r8 = *(const short8*)(bs + 12288 + s*128 + j0*2);
      short8 k8 = *(const short8*)(bs + 14336 + s*128 + j0*2);
      float vi = b2f(*(const u16*)(bs + 16384 + s*128 + row*2));
      float yv = 0.f;
      #pragma unroll
      for (int e=0;e<4;++e){
        float Sq = S[e]*d0v[e] + sa*b0v[e] + vi*b2fs(k8[e]);
        S[e] = Sq;
        yv += Sq*b2fs(r8[e]);
      }
      #pragma unroll
      for (int e=0;e<4;++e){
        float Sq = S[4+e]*d1v[e] + sa*b1v[e] + vi*b2fs(k8[4+e]);
        S[4+e] = Sq;
        yv += Sq*b2fs(r8[4+e]);
      }
      ycur[s] = rdx8(yv);
    }
    #pragma unroll
    for (int s=0;s<RCH;++s) yprev[s] = ycur[s];
    cur = (cur+1==3)?0:cur+1;
  }
#undef RSTAGE
  {
    int t0 = (RNC-1)*RCH;
    #pragma unroll
    for (int s=0;s<RCH;++s) if (g==0) y[yb + (size_t)(t0+s)*CC] = f2b(yprev[s]);
  }
}

// ---------------- groupnorm + rk*v + gate -> z bf16
__global__ __launch_bounds__(256) void k_gn(
  const u16* __restrict__ y, const u16* __restrict__ rb, const u16* __restrict__ kb,
  const u16* __restrict__ vb, const float* __restrict__ r_k,
  const float* __restrict__ gnw, const float* __restrict__ gnb,
  const u16* __restrict__ gg, u16* __restrict__ z)
{
  int idx = blockIdx.x*4 + (threadIdx.x>>6);
  int l = threadIdx.x&63;
  int m = idx>>5, h = idx&31;
  int c = h*64 + l;
  size_t mo = (size_t)m*CC + c;
  float yv = b2f(y[mo]);
  float s = yv;
  #pragma unroll
  for (int o=32;o;o>>=1) s += __shfl_xor(s,o);
  float mean = s*(1.f/64.f);
  float dv = yv - mean;
  float vs = dv*dv;
  #pragma unroll
  for (int o=32;o;o>>=1) vs += __shfl_xor(vs,o);
  float gn = dv*rsqrtf(vs*(1.f/64.f) + 6.4e-4f)*gnw[c] + gnb[c];
  size_t ro = ((size_t)((m/TT)*HH + h)*TT + (m%TT))*64 + l;
  float rv=b2f(rb[ro]), kv=b2f(kb[ro]), vv=b2f(vb[ro]);
  float p = rv*kv*r_k[c];
  #pragma unroll
  for (int o=32;o;o>>=1) p += __shfl_xor(p,o);
  z[mo] = f2b((gn + p*vv)*b2f(gg[mo]));
}

extern "C" void kernel_launch(void* const* d_in, const int* in_sizes, int n_in,
                              void* d_out, int out_size, void* d_ws, size_t ws_size,
                              hipStream_t stream)
{
  (void)out_size;
  const float* x      = (const float*)d_in[0];
  const float* v_first= (const float*)d_in[1];
  const float* ln1_w  = (const float*)d_in[2];
  const float* ln1_b  = (const float*)d_in[3];
  const float* ln2_w  = (const float*)d_in[4];
  const float* ln2_b  = (const float*)d_in[5];
  const float* x_r    = (const float*)d_in[6];
  const float* x_w    = (const float*)d_in[7];
  const float* x_k    = (const float*)d_in[8];
  const float* x_v    = (const float*)d_in[9];
  const float* x_a    = (const float*)d_in[10];
  const float* x_g    = (const float*)d_in[11];
  const float* w0     = (const float*)d_in[12];
  const float* w1     = (const float*)d_in[13];
  const float* w2     = (const float*)d_in[14];
  const float* a0     = (const float*)d_in[15];
  const float* a1     = (const float*)d_in[16];
  const float* a2     = (const float*)d_in[17];
  const float* v0     = (const float*)d_in[18];
  const float* v1     = (const float*)d_in[19];
  const float* v2     = (const float*)d_in[20];
  const float* g1     = (const float*)d_in[21];
  const float* g2     = (const float*)d_in[22];
  const float* k_k    = (const float*)d_in[23];
  const float* k_a    = (const float*)d_in[24];
  const float* r_k    = (const float*)d_in[25];
  const float* W_r    = (const float*)d_in[26];
  const float* W_k    = (const float*)d_in[27];
  const float* W_v    = (const float*)d_in[28];
  const float* W_o    = (const float*)d_in[29];
  const float* gn_w   = (const float*)d_in[30];
  const float* gn_b   = (const float*)d_in[31];
  const float* ffn_x_k= (const float*)d_in[32];
  const float* W_key  = (const float*)d_in[33];
  const float* W_val  = (const float*)d_in[34];

  const size_t ME = (size_t)MM*CC;
  float* outF = (float*)d_out;

  bool ok = (n_in==35)
    && in_sizes[0]==6291456 && in_sizes[1]==6291456 && in_sizes[2]==2048
    && in_sizes[12]==2048 && in_sizes[13]==196608 && in_sizes[14]==196608
    && in_sizes[16]==196608 && in_sizes[19]==131072 && in_sizes[21]==524288
    && in_sizes[25]==2048 && in_sizes[26]==4194304 && in_sizes[33]==16777216
    && in_sizes[34]==16777216;
  if (!ok){
    k_fillf<<<2048, 256, 0, stream>>>(outF, 1099511627776.f, (int)ME);
    return;
  }

  constexpr size_t WS_NEED = 125829120 + 12582912;
  if (ws_size < WS_NEED){
    k_fillf<<<2048, 256, 0, stream>>>(outF, (float)(1u<<21) * (float)(ws_size>>20), (int)ME);
    return;
  }
  char* ws = (char*)d_ws;
  float* decay = (float*)(ws + 0);
  float* x1    = (float*)(ws + 0);
  u16* xn   = (u16*)(ws + 25165824);
  u16* WT   = (u16*)(ws + 25165824);
  float* bf32 = (float*)(ws + 25165824);
  u16* xw  = (u16*)(ws + 37748736);
  u16* xr  = (u16*)(ws + 37748736);
  u16* xn2 = (u16*)(ws + 37748736);
  float* af32 = (float*)(ws + 50331648);
  u16* xa  = (u16*)(ws + 50331648);
  u16* xk  = (u16*)(ws + 50331648);
  u16* xv  = (u16*)(ws + 62914560);
  u16* kf  = (u16*)(ws + 62914560);
  u16* xg  = (u16*)(ws + 75497472);
  u16* rsc = (u16*)(ws + 75497472);
  char* Fs = ws + 88080384;
  u16* B1T = (u16*)(Fs);
  u16* w2T = (u16*)(Fs + 2621440);
  u16* a2T = (u16*)(Fs + 3014656);
  u16* v2T = (u16*)(Fs + 3407872);
  u16* g2T = (u16*)(Fs + 3670016);
  u16* H1b = (u16*)(Fs + 4718592);
  u16* ksc = (u16*)(ws + 88080384);
  u16* asc = (u16*)(ws + 100663296);
  u16* ybuf= (u16*)(ws + 100663296);
  u16* gsc = (u16*)(ws + 113246208);
  u16* zbuf= (u16*)(ws + 113246208);
  u16* xcm = (u16*)(ws + 113246208);
  u16* WbigT = (u16*)(ws + 25165824);
  u16* outG = (u16*)(ws + 125829120);
  u16* vsc   = (u16*)d_out;
  u16* WrkvT = ((u16*)d_out) + ME;

  auto GEMM = [&](const u16* a0_, const u16* a1_, const u16* a2_,
                  int amode, int lda_, const u16* bt, int ldb_,
                  void* c0_, void* c1_, void* c2_, int ldc_,
                  int N_, int K_, int em, const float* aux_){
    k_gemm<<<dim3(N_/128, MM/128), 256, 0, stream>>>(a0_,a1_,a2_,amode,lda_,bt,ldb_,c0_,c1_,c2_,ldc_,K_,em,aux_);
  };
  dim3 tb(32,8);

  k_lnb<<<MM, 256, 0, stream>>>(x, ln1_w, ln1_b, xn);
  k_mixA<<<MM, 256, 0, stream>>>(xn, x_w, x_a, x_v, x_g, xw, xa, xv, xg);
  hipMemsetAsync(B1T, 0, 2621440, stream);
  k_tpose<<<dim3(3,64), tb, 0, stream>>>(w1, 2048,  96, B1T + 0*2048,   2048);
  k_tpose<<<dim3(3,64), tb, 0, stream>>>(a1, 2048,  96, B1T + 128*2048, 2048);
  k_tpose<<<dim3(2,64), tb, 0, stream>>>(v1, 2048,  64, B1T + 256*2048, 2048);
  k_tpose<<<dim3(8,64), tb, 0, stream>>>(g1, 2048, 256, B1T + 384*2048, 2048);
  k_tpose<<<dim3(64,3), tb, 0, stream>>>(w2,   96, 2048, w2T,  96);
  k_tpose<<<dim3(64,3), tb, 0, stream>>>(a2,   96, 2048, a2T,  96);
  k_tpose<<<dim3(64,2), tb, 0, stream>>>(v2,   64, 2048, v2T,  64);
  k_tpose<<<dim3(64,8), tb, 0, stream>>>(g2,  256, 2048, g2T, 256);
  GEMM(xw, xa, xv, 1, 2048, B1T, 2048, H1b, nullptr, nullptr, 640, 384, 2048, 7, nullptr);
  GEMM(xg, xg, xg, 0, 2048, B1T + 384*2048, 2048, H1b, nullptr, nullptr, 640, 256, 2048, 11, nullptr);
  GEMM(H1b + 0,   H1b, H1b, 0, 640, w2T,  96, decay, nullptr, nullptr, 2048, 2048,  96, 1, w0);
  GEMM(H1b + 128, H1b, H1b, 0, 640, a2T,  96, asc,   nullptr, nullptr, 2048, 2048,  96, 9, a0);
  GEMM(H1b + 256, H1b, H1b, 0, 640, v2T,  64, gsc,   nullptr, nullptr, 2048, 2048,  64, 9, v0);
  GEMM(H1b + 384, H1b, H1b, 0, 640, g2T, 256, outG,  nullptr, nullptr, 2048, 2048, 256, 6, nullptr);
  k_mixB<<<MM, 256, 0, stream>>>(xn, x_r, x_k, xr, xk);
  k_tpose<<<dim3(64,64), tb, 0, stream>>>(W_r, 2048, 2048, WrkvT,               2048);
  k_tpose<<<dim3(64,64), tb, 0, stream>>>(W_k, 2048, 2048, WrkvT + 2048*2048,   2048);
  k_tpose<<<dim3(64,64), tb, 0, stream>>>(W_v, 2048, 2048, WrkvT + 2*2048*2048, 2048);
  GEMM(xr, xk, xv, 2, 2048, WrkvT, 2048, rsc, ksc, vsc, 2048, 6144, 2048, 10, nullptr);
  k_make_rec3<<<MM*HH/4, 256, 0, stream>>>(ksc, vsc, asc, gsc, af32, bf32, v_first, k_k, k_a);
  k_rwkv<<<256, 256, 0, stream>>>(decay, af32, bf32, rsc, ksc, vsc, ybuf);
  k_gn<<<MM*HH/4, 256, 0, stream>>>(ybuf, rsc, ksc, vsc, r_k, gn_w, gn_b, outG, zbuf);
  k_tpose<<<dim3(64,64), tb, 0, stream>>>(W_o, 2048, 2048, WT, 2048);
  GEMM(zbuf, zbuf, zbuf, 0, 2048, WT, 2048, x1, nullptr, nullptr, 2048, 2048, 2048, 3, x);
  k_lnb<<<MM, 256, 0, stream>>>(x1, ln2_w, ln2_b, xn2);
  k_mix1<<<MM, 256, 0, stream>>>(xn2, ffn_x_k, xcm);
  k_tpose<<<dim3(256,64), tb, 0, stream>>>(W_key, 2048, 8192, WbigT, 2048);
  GEMM(xcm, xcm, xcm, 0, 2048, WbigT, 2048, kf, nullptr, nullptr, 8192, 8192, 2048, 4, nullptr);
  k_tpose<<<dim3(64,256), tb, 0, stream>>>(W_val, 8192, 2048, WbigT, 8192);
  GEMM(kf, kf, kf, 0, 8192, WbigT, 8192, outF, nullptr, nullptr, 2048, 2048, 8192, 3, x1);
  hipMemcpyAsync(outF + ME, v_first, ME*sizeof(float), hipMemcpyDeviceToDevice, stream);
}